// Round 7
// baseline (378.523 us; speedup 1.0000x reference)
//
#include <hip/hip_runtime.h>
#include <cstdint>

// ---------------------------------------------------------------------------
// CrossAttentionBlock: q/k/v proj (bf16 MFMA; K/V rows zeroed where masked) ->
// flash attention (32x32 MFMA, fixed-m softmax, REGISTER-DIRECT K/V: no LDS,
// no barriers, pure-sum partials) -> merge(+transpose) -> o proj (+residual)
// -> LayerNorm.   B=2, SQ=1024, SKV=4096, E=1024, H=16, D=64.
// Fixed-m softmax: p = 2^(s*log2e/8 - 10). Masked kv have K=V=0 => s==0
// exactly => p = 2^-10 exactly; contributes 0 to O and n_masked*2^-10 to l,
// subtracted at merge.
// R5 lesson: never force launch_bounds below the live set (spill disaster).
// R6 lesson: per-tile __syncthreads+vmcnt(0) drain dominates when compute per
// barrier is small -> this version has ZERO barriers in the attn main loop.
// ---------------------------------------------------------------------------

typedef __bf16 bf16x8_t  __attribute__((ext_vector_type(8)));
typedef float  f32x4_t   __attribute__((ext_vector_type(4)));
typedef float  f32x16_t  __attribute__((ext_vector_type(16)));

#define E_DIM 1024
#define NH    16
#define HD    64
#define SCALE_L2E 0.1803368804f   // (1/8) * log2(e)
#define FIXM  10.0f

__device__ __forceinline__ unsigned short f32_bf16(float f) {
    union { float f; unsigned int u; } v; v.f = f;
    unsigned int u = v.u;
    unsigned int r = (u + 0x7fffu + ((u >> 16) & 1u)) >> 16;  // RNE
    return (unsigned short)r;
}

__device__ __forceinline__ unsigned pack_bf16(float a, float b) {
    __bf16 x = (__bf16)a, y = (__bf16)b;
    unsigned short ux = __builtin_bit_cast(unsigned short, x);
    unsigned short uy = __builtin_bit_cast(unsigned short, y);
    return (unsigned)ux | ((unsigned)uy << 16);
}

// async global->LDS, 16B per lane; lds base must be wave-uniform
__device__ __forceinline__ void gld16(const unsigned short* g, unsigned short* l) {
    __builtin_amdgcn_global_load_lds(
        (const __attribute__((address_space(1))) unsigned int*)g,
        (__attribute__((address_space(3))) unsigned int*)l, 16, 0, 0);
}

__device__ __forceinline__ bf16x8_t ld16g(const unsigned short* p) {
    union { uint4 u; bf16x8_t f; } v;
    v.u = *reinterpret_cast<const uint4*>(p);
    return v.f;
}

// ---------------- fused fp32 -> bf16 casts (all 6 tensors) -----------------
__global__ void cast_all(const float* __restrict__ q, const float* __restrict__ kv,
                         const float* __restrict__ wq, const float* __restrict__ wk,
                         const float* __restrict__ wv, const float* __restrict__ wo,
                         unsigned short* __restrict__ Xq, unsigned short* __restrict__ Xkv,
                         unsigned short* __restrict__ Wqb, unsigned short* __restrict__ Wkb,
                         unsigned short* __restrict__ Wvb, unsigned short* __restrict__ Wob) {
    long i = (long)blockIdx.x * 256 + threadIdx.x;   // float4 index
    const float* src; unsigned short* dst; long off;
    if (i < 2621440) {
        if (i < 524288) { src = q;  dst = Xq;  off = i; }
        else            { src = kv; dst = Xkv; off = i - 524288; }
    } else {
        long j = i - 2621440;
        int w = (int)(j >> 18); off = j & 262143;
        src = (w == 0) ? wq : (w == 1) ? wk : (w == 2) ? wv : wo;
        dst = (w == 0) ? Wqb : (w == 1) ? Wkb : (w == 2) ? Wvb : Wob;
    }
    float4 v = reinterpret_cast<const float4*>(src)[off];
    ushort4 o;
    o.x = f32_bf16(v.x); o.y = f32_bf16(v.y);
    o.z = f32_bf16(v.z); o.w = f32_bf16(v.w);
    reinterpret_cast<ushort4*>(dst)[off] = o;
}

// ---------------- count masked kv per batch -> n_masked * 2^-10 ------------
__global__ void count_mask(const int* __restrict__ m, float* __restrict__ Sub) {
    __shared__ int red[4];
    int b = blockIdx.x, t = threadIdx.x;
    int s = 0;
#pragma unroll
    for (int k = 0; k < 16; k++) s += (m[b * 4096 + k * 256 + t] != 0);
#pragma unroll
    for (int off = 32; off >= 1; off >>= 1) s += __shfl_xor(s, off, 64);
    if ((t & 63) == 0) red[t >> 6] = s;
    __syncthreads();
    if (t == 0)
        Sub[b] = (float)(4096 - (red[0] + red[1] + red[2] + red[3])) * 0.0009765625f;
}

// ---------------- GEMM: C = A @ W^T + bias (m97-style staging) -------------
// mode 0: [B,H,S,D] (Q, no mask).  mode 1: [B,H,S,D], masked rows zeroed (K).
// mode 2: [B,H,D,S] (V^T), masked cols zeroed.
#define BM 128
#define BN 128
#define BK 64

__global__ __launch_bounds__(256) void gemm_qkv(
    const unsigned short* __restrict__ A,
    const unsigned short* __restrict__ W,
    const float* __restrict__ bias,
    unsigned short* __restrict__ out,
    int lgS, int mode, const int* __restrict__ kvm)
{
    __shared__ __align__(16) unsigned short As[BM * BK];
    __shared__ __align__(16) unsigned short Bs[BN * BK];
    int tid  = threadIdx.x;
    int m0   = blockIdx.y * BM;
    int n0   = blockIdx.x * BN;
    int lane = tid & 63;
    int wvu  = __builtin_amdgcn_readfirstlane(tid >> 6);
    int l15  = lane & 15, quad = lane >> 4, x7 = l15 & 7;
    int wm   = ((tid >> 6) >> 1) * 64, wn = ((tid >> 6) & 1) * 64;

    f32x4_t acc[4][4];
#pragma unroll
    for (int i = 0; i < 4; i++)
#pragma unroll
        for (int j = 0; j < 4; j++) acc[i][j] = (f32x4_t)(0.f);

    for (int k0 = 0; k0 < 1024; k0 += BK) {
        __syncthreads();
#pragma unroll
        for (int i = 0; i < 4; i++) {
            int s = (i * 4 + wvu) * 64 + lane;
            int row = s >> 3, pcol = ((s & 7) ^ (row & 7)) << 3;
            gld16(&A[(long)(m0 + row) * 1024 + k0 + pcol], &As[(i * 4 + wvu) * 512]);
            gld16(&W[(long)(n0 + row) * 1024 + k0 + pcol], &Bs[(i * 4 + wvu) * 512]);
        }
        __syncthreads();
        const char* Ab = (const char*)As;
        const char* Bb = (const char*)Bs;
#pragma unroll
        for (int ks = 0; ks < 2; ks++) {
            int pos = (((ks << 2) + quad) ^ x7) << 4;
            bf16x8_t af[4], bf[4];
#pragma unroll
            for (int mi = 0; mi < 4; mi++)
                af[mi] = *reinterpret_cast<const bf16x8_t*>(
                    Ab + (wm + mi * 16 + l15) * 128 + pos);
#pragma unroll
            for (int ni = 0; ni < 4; ni++)
                bf[ni] = *reinterpret_cast<const bf16x8_t*>(
                    Bb + (wn + ni * 16 + l15) * 128 + pos);
#pragma unroll
            for (int mi = 0; mi < 4; mi++)
#pragma unroll
                for (int ni = 0; ni < 4; ni++)
                    acc[mi][ni] = __builtin_amdgcn_mfma_f32_16x16x32_bf16(
                        af[mi], bf[ni], acc[mi][ni], 0, 0, 0);
        }
    }
    int Smask = (1 << lgS) - 1;
    if (mode == 0) {
#pragma unroll
        for (int mi = 0; mi < 4; mi++)
#pragma unroll
            for (int ni = 0; ni < 4; ni++) {
                int n = n0 + wn + ni * 16 + l15;
                float bv = bias[n];
                int h = n >> 6, d = n & 63;
#pragma unroll
                for (int r = 0; r < 4; r++) {
                    int mg = m0 + wm + mi * 16 + quad * 4 + r;
                    int b = mg >> lgS, s = mg & Smask;
                    out[(((b * NH + h) << lgS) + s) * HD + d] =
                        f32_bf16(acc[mi][ni][r] + bv);
                }
            }
    } else if (mode == 1) {
#pragma unroll
        for (int mi = 0; mi < 4; mi++)
#pragma unroll
            for (int ni = 0; ni < 4; ni++) {
                int n = n0 + wn + ni * 16 + l15;
                float bv = bias[n];
                int h = n >> 6, d = n & 63;
#pragma unroll
                for (int r = 0; r < 4; r++) {
                    int mg = m0 + wm + mi * 16 + quad * 4 + r;
                    int b = mg >> lgS, s = mg & Smask;
                    unsigned short val = kvm[(b << lgS) + s]
                        ? f32_bf16(acc[mi][ni][r] + bv) : (unsigned short)0;
                    out[(((b * NH + h) << lgS) + s) * HD + d] = val;
                }
            }
    } else {
#pragma unroll
        for (int mi = 0; mi < 4; mi++)
#pragma unroll
            for (int ni = 0; ni < 4; ni++) {
                int n = n0 + wn + ni * 16 + l15;
                float bv = bias[n];
                int h = n >> 6, d = n & 63;
                int mg0 = m0 + wm + mi * 16 + quad * 4;
                int b = mg0 >> lgS, s = mg0 & Smask;
                int4 mk = *reinterpret_cast<const int4*>(&kvm[(b << lgS) + s]);
                ushort4 w;
                w.x = mk.x ? f32_bf16(acc[mi][ni][0] + bv) : (unsigned short)0;
                w.y = mk.y ? f32_bf16(acc[mi][ni][1] + bv) : (unsigned short)0;
                w.z = mk.z ? f32_bf16(acc[mi][ni][2] + bv) : (unsigned short)0;
                w.w = mk.w ? f32_bf16(acc[mi][ni][3] + bv) : (unsigned short)0;
                *reinterpret_cast<ushort4*>(
                    &out[(((b * NH + h) * HD + d) << lgS) + s]) = w;
            }
    }
}

// ---------------- O-proj GEMM + bias + residual -> fp32 --------------------
__global__ __launch_bounds__(256) void gemm_oproj(
    const unsigned short* __restrict__ A,
    const unsigned short* __restrict__ W,
    const float* __restrict__ bias,
    const float* __restrict__ resid,
    float* __restrict__ xout)
{
    __shared__ __align__(16) unsigned short As[BM * BK];
    __shared__ __align__(16) unsigned short Bs[BN * BK];
    int tid  = threadIdx.x;
    int m0   = blockIdx.y * BM;
    int n0   = blockIdx.x * BN;
    int lane = tid & 63;
    int wvu  = __builtin_amdgcn_readfirstlane(tid >> 6);
    int l15  = lane & 15, quad = lane >> 4, x7 = l15 & 7;
    int wm   = ((tid >> 6) >> 1) * 64, wn = ((tid >> 6) & 1) * 64;

    f32x4_t acc[4][4];
#pragma unroll
    for (int i = 0; i < 4; i++)
#pragma unroll
        for (int j = 0; j < 4; j++) acc[i][j] = (f32x4_t)(0.f);

    for (int k0 = 0; k0 < 1024; k0 += BK) {
        __syncthreads();
#pragma unroll
        for (int i = 0; i < 4; i++) {
            int s = (i * 4 + wvu) * 64 + lane;
            int row = s >> 3, pcol = ((s & 7) ^ (row & 7)) << 3;
            gld16(&A[(long)(m0 + row) * 1024 + k0 + pcol], &As[(i * 4 + wvu) * 512]);
            gld16(&W[(long)(n0 + row) * 1024 + k0 + pcol], &Bs[(i * 4 + wvu) * 512]);
        }
        __syncthreads();
        const char* Ab = (const char*)As;
        const char* Bb = (const char*)Bs;
#pragma unroll
        for (int ks = 0; ks < 2; ks++) {
            int pos = (((ks << 2) + quad) ^ x7) << 4;
            bf16x8_t af[4], bf[4];
#pragma unroll
            for (int mi = 0; mi < 4; mi++)
                af[mi] = *reinterpret_cast<const bf16x8_t*>(
                    Ab + (wm + mi * 16 + l15) * 128 + pos);
#pragma unroll
            for (int ni = 0; ni < 4; ni++)
                bf[ni] = *reinterpret_cast<const bf16x8_t*>(
                    Bb + (wn + ni * 16 + l15) * 128 + pos);
#pragma unroll
            for (int mi = 0; mi < 4; mi++)
#pragma unroll
                for (int ni = 0; ni < 4; ni++)
                    acc[mi][ni] = __builtin_amdgcn_mfma_f32_16x16x32_bf16(
                        af[mi], bf[ni], acc[mi][ni], 0, 0, 0);
        }
    }
#pragma unroll
    for (int mi = 0; mi < 4; mi++)
#pragma unroll
        for (int ni = 0; ni < 4; ni++) {
            int n = n0 + wn + ni * 16 + l15;
            float bv = bias[n];
#pragma unroll
            for (int r = 0; r < 4; r++) {
                int mg = m0 + wm + mi * 16 + quad * 4 + r;
                xout[mg * 1024 + n] = acc[mi][ni][r] + bv + resid[mg * 1024 + n];
            }
        }
}

// ---------------- flash attention: register-direct, barrier-free -----------
// grid 1024 blocks of 256 (4 waves).  Block = 64 q of one (b,h) x kv-half
// (2048, 16 tiles of 128).  Wave w: q-subtile = w&1 (32 q), tile-kv-half =
// w>>1 (64 kv).  K/V fragments load straight from global (L2-resident via
// XCD grouping).  No __shared__, no __syncthreads in the whole kernel.
// Partial index p = blockhalf*2 + wave_kvhalf (4 partials per (bh,q)).
__global__ __launch_bounds__(256) void attn_kernel(
    const unsigned short* __restrict__ Q,   // [B,NH,1024,64]
    const unsigned short* __restrict__ K,   // [B,NH,4096,64]  masked rows = 0
    const unsigned short* __restrict__ VT,  // [B,NH,64,4096]  masked cols = 0
    float* __restrict__ Osc,                // [4][32][64][1024] fp32 partial O^T
    float* __restrict__ Lsc)                // [4][32][1024] partial l
{
    int tid  = threadIdx.x;
    int lane = tid & 63;
    int w    = tid >> 6;
    int l31  = lane & 31, hw = lane >> 5;
    int qsub = w & 1, kvh = w >> 1;

    // XCD-grouped: 4 (b,h) per XCD; q-tiles and halves of one bh share L2
    int bid  = blockIdx.x;
    int xcd  = bid & 7, gidx = bid >> 3;
    int bh   = xcd * 4 + (gidx & 3);
    int rest = gidx >> 2;                    // 0..31
    int q0   = (rest & 15) * 64;
    int bhalf = rest >> 4;

    const unsigned short* Kb = K + ((long)bh * 4096 + bhalf * 2048) * HD;
    const unsigned short* Vb = VT + (long)bh * HD * 4096 + bhalf * 2048;
    const unsigned short* Qb = Q + ((long)bh * 1024 + q0) * HD;

    // Q fragments (B-operand): B[n=q=l31][k=hw*8+j], 4 k-chunks of 16
    bf16x8_t qfr[4];
#pragma unroll
    for (int ks = 0; ks < 4; ks++)
        qfr[ks] = ld16g(Qb + (qsub * 32 + l31) * HD + ks * 16 + hw * 8);

    f32x16_t oacc[2];
    oacc[0] = (f32x16_t)(0.f); oacc[1] = (f32x16_t)(0.f);
    float l_run = 0.f;

#pragma unroll 2
    for (int kt = 0; kt < 16; kt++) {
        int kvb = kt * 128 + kvh * 64;       // wave's 64-kv strip-pair
#pragma unroll
        for (int s2 = 0; s2 < 2; s2++) {
            // ---- S^T: C[kv32][q32] for strip s2 ----
            const unsigned short* kr = Kb + (long)(kvb + s2 * 32 + l31) * HD;
            f32x16_t sa = (f32x16_t)(0.f);
#pragma unroll
            for (int ks = 0; ks < 4; ks++) {
                bf16x8_t kf = ld16g(kr + ks * 16 + hw * 8);
                sa = __builtin_amdgcn_mfma_f32_32x32x16_bf16(kf, qfr[ks], sa, 0, 0, 0);
            }
            // ---- fixed-m softmax: p = 2^(s*c - 10) ----
            float pv[16];
            float rs = 0.f;
#pragma unroll
            for (int r = 0; r < 16; r++) {
                pv[r] = exp2f(fmaf(sa[r], SCALE_L2E, -FIXM));
                rs += pv[r];
            }
            l_run += rs;
            unsigned pku[8];
#pragma unroll
            for (int s4 = 0; s4 < 4; s4++) {
                pku[s4 * 2 + 0] = pack_bf16(pv[s4 * 4 + 0], pv[s4 * 4 + 1]);
                pku[s4 * 2 + 1] = pack_bf16(pv[s4 * 4 + 2], pv[s4 * 4 + 3]);
            }
            // ---- PV: O^T[d][q] += V^T · P over this 32-kv strip ----
#pragma unroll
            for (int ks2 = 0; ks2 < 2; ks2++) {
                int s_lo = ks2 * 2, s_own = ks2 * 2 + hw;
                unsigned send0 = hw ? pku[s_lo * 2 + 0] : pku[(s_lo + 1) * 2 + 0];
                unsigned send1 = hw ? pku[s_lo * 2 + 1] : pku[(s_lo + 1) * 2 + 1];
                unsigned recv0 = __shfl_xor((int)send0, 32, 64);
                unsigned recv1 = __shfl_xor((int)send1, 32, 64);
                union { uint4 u; bf16x8_t f; } bw;
                bw.u.x = hw ? recv0 : pku[s_own * 2 + 0];
                bw.u.y = hw ? recv1 : pku[s_own * 2 + 1];
                bw.u.z = hw ? pku[s_own * 2 + 0] : recv0;
                bw.u.w = hw ? pku[s_own * 2 + 1] : recv1;
                int kc = kvb + s2 * 32 + ks2 * 16 + hw * 8;
#pragma unroll
                for (int ds = 0; ds < 2; ds++) {
                    bf16x8_t va = ld16g(Vb + (long)(ds * 32 + l31) * 4096 + kc);
                    oacc[ds] = __builtin_amdgcn_mfma_f32_32x32x16_bf16(
                        va, bw.f, oacc[ds], 0, 0, 0);
                }
            }
        }
    }

    // ---- epilogue: per-wave partial, coalesced [d][q] stores ----
    l_run += __shfl_xor(l_run, 32, 64);
    int p = bhalf * 2 + kvh;
    int q = q0 + qsub * 32 + l31;
    if (hw == 0)
        Lsc[((long)p * 32 + bh) * 1024 + q] = l_run;
    long obase = (((long)p * 32 + bh) * 64) * 1024;
#pragma unroll
    for (int ds = 0; ds < 2; ds++)
#pragma unroll
        for (int r = 0; r < 16; r++) {
            int d = ds * 32 + (r & 3) + 8 * (r >> 2) + 4 * hw;
            Osc[obase + (long)d * 1024 + q] = oacc[ds][r];
        }
}

// ---------------- merge 4 partials, normalize, transpose to AO -------------
// grid (16 qtiles, 32 bh) x 256.  Reads Osc [p][bh][d][q] coalesced (lane=q),
// LDS-transposes 64x64, writes AO [b][q][h*64+d] coalesced.
__global__ __launch_bounds__(256) void attn_merge(
    const float* __restrict__ Osc, const float* __restrict__ Lsc,
    const float* __restrict__ Sub, unsigned short* __restrict__ AO)
{
    __shared__ unsigned short T[64 * 66];
    int t = threadIdx.x, w = t >> 6, lane = t & 63;
    int bh = blockIdx.y, b = bh >> 4, h = bh & 15;
    int q0 = blockIdx.x * 64;
    int q = q0 + lane;

    float ls = Lsc[(long)(0 * 32 + bh) * 1024 + q]
             + Lsc[(long)(1 * 32 + bh) * 1024 + q]
             + Lsc[(long)(2 * 32 + bh) * 1024 + q]
             + Lsc[(long)(3 * 32 + bh) * 1024 + q] - Sub[b];
    float inv = __builtin_amdgcn_rcpf(ls);
    inv = inv * (2.f - ls * inv);            // NR refine

#pragma unroll
    for (int dd = 0; dd < 16; dd++) {
        int d = w * 16 + dd;
        long base = (long)bh * 64 * 1024 + (long)d * 1024 + q;
        float o = Osc[base]
                + Osc[base + 32l * 64 * 1024]
                + Osc[base + 64l * 64 * 1024]
                + Osc[base + 96l * 64 * 1024];
        T[lane * 66 + d] = f32_bf16(o * inv);
    }
    __syncthreads();
    // output: thread copies 16 u16 of row q2 = t>>2, cols c16 = (t&3)*16
    int q2 = t >> 2, c16 = (t & 3) * 16;
    unsigned ov[8];
#pragma unroll
    for (int j = 0; j < 8; j++)
        ov[j] = *reinterpret_cast<const unsigned*>(&T[q2 * 66 + c16 + j * 2]);
    unsigned short* dst = &AO[((long)(b * 1024 + q0 + q2)) * E_DIM + h * HD + c16];
    reinterpret_cast<uint4*>(dst)[0] = make_uint4(ov[0], ov[1], ov[2], ov[3]);
    reinterpret_cast<uint4*>(dst)[1] = make_uint4(ov[4], ov[5], ov[6], ov[7]);
}

// ---------------- LayerNorm over E=1024 ------------------------------------
__global__ __launch_bounds__(256) void ln_kernel(
    const float* __restrict__ x, const float* __restrict__ g,
    const float* __restrict__ be, float* __restrict__ out)
{
    __shared__ float red[8];
    int row = blockIdx.x, tid = threadIdx.x;
    float4 v = reinterpret_cast<const float4*>(x)[row * 256 + tid];
    float s  = v.x + v.y + v.z + v.w;
    float sq = v.x * v.x + v.y * v.y + v.z * v.z + v.w * v.w;
#pragma unroll
    for (int off = 32; off >= 1; off >>= 1) {
        s  += __shfl_xor(s,  off, 64);
        sq += __shfl_xor(sq, off, 64);
    }
    if ((tid & 63) == 0) { red[tid >> 6] = s; red[4 + (tid >> 6)] = sq; }
    __syncthreads();
    s  = red[0] + red[1] + red[2] + red[3];
    sq = red[4] + red[5] + red[6] + red[7];
    float mu  = s * (1.f / 1024.f);
    float var = sq * (1.f / 1024.f) - mu * mu;
    float rs  = rsqrtf(var + 1e-5f);
    int c = tid * 4;
    float4 o;
    o.x = (v.x - mu) * rs * g[c]     + be[c];
    o.y = (v.y - mu) * rs * g[c + 1] + be[c + 1];
    o.z = (v.z - mu) * rs * g[c + 2] + be[c + 2];
    o.w = (v.w - mu) * rs * g[c + 3] + be[c + 3];
    reinterpret_cast<float4*>(out)[row * 256 + tid] = o;
}

// ---------------------------------------------------------------------------
extern "C" void kernel_launch(void* const* d_in, const int* in_sizes, int n_in,
                              void* d_out, int out_size, void* d_ws, size_t ws_size,
                              hipStream_t stream) {
    const float* query     = (const float*)d_in[0];
    const float* key_value = (const float*)d_in[1];
    const int*   kv_mask   = (const int*)d_in[2];
    const float* Wq = (const float*)d_in[3];
    const float* bq = (const float*)d_in[4];
    const float* Wk = (const float*)d_in[5];
    const float* bk = (const float*)d_in[6];
    const float* Wv = (const float*)d_in[7];
    const float* bv = (const float*)d_in[8];
    const float* Wo = (const float*)d_in[9];
    const float* bo = (const float*)d_in[10];
    const float* ln_g = (const float*)d_in[11];
    const float* ln_b = (const float*)d_in[12];
    float* out = (float*)d_out;

    // workspace layout (MiB). Osc (32 MB) overlays the cast buffers, which
    // are dead before attn_kernel runs (stream-ordered).
    char* ws = (char*)d_ws;
    unsigned short* Xq  = (unsigned short*)(ws);                     // 0-4
    unsigned short* Xkv = (unsigned short*)(ws + (4ll  << 20));      // 4-20
    unsigned short* Wqb = (unsigned short*)(ws + (20ll << 20));      // 20-22
    unsigned short* Wkb = (unsigned short*)(ws + (22ll << 20));      // 22-24
    unsigned short* Wvb = (unsigned short*)(ws + (24ll << 20));      // 24-26
    float*          Osc = (float*)(ws);                              // 0-32 (after gemms)
    unsigned short* Kh  = (unsigned short*)(ws + (32ll << 20));      // 32-48
    unsigned short* VTh = (unsigned short*)(ws + (48ll << 20));      // 48-64
    unsigned short* AO  = (unsigned short*)(ws + (64ll << 20));      // 64-68
    float*          Xr  = (float*)(ws + (68ll << 20));               // 68-76
    float*          Lsc = (float*)(ws + (76ll << 20));               // 76-76.5
    float*          Sub = (float*)(ws + (77ll << 20));               // tiny
    unsigned short* Qh  = (unsigned short*)(ws + (80ll << 20));      // 80-84
    unsigned short* Wob = (unsigned short*)(ws + (84ll << 20));      // 84-86

    cast_all<<<14336, 256, 0, stream>>>(query, key_value, Wq, Wk, Wv, Wo,
                                        Xq, Xkv, Wqb, Wkb, Wvb, Wob);
    count_mask<<<2, 256, 0, stream>>>(kv_mask, Sub);

    gemm_qkv<<<dim3(8, 16), 256, 0, stream>>>(Xq,  Wqb, bq, Qh,  10, 0, kv_mask);
    gemm_qkv<<<dim3(8, 64), 256, 0, stream>>>(Xkv, Wkb, bk, Kh,  12, 1, kv_mask);
    gemm_qkv<<<dim3(8, 64), 256, 0, stream>>>(Xkv, Wvb, bv, VTh, 12, 2, kv_mask);

    attn_kernel<<<1024, 256, 0, stream>>>(Qh, Kh, VTh, Osc, Lsc);
    attn_merge<<<dim3(16, 32), 256, 0, stream>>>(Osc, Lsc, Sub, AO);

    gemm_oproj<<<dim3(8, 16), 256, 0, stream>>>(AO, Wob, bo, query, Xr);

    ln_kernel<<<2048, 256, 0, stream>>>(Xr, ln_g, ln_b, out);
}

// Round 8
// 298.986 us; speedup vs baseline: 1.2660x; 1.2660x over previous
//
#include <hip/hip_runtime.h>
#include <cstdint>

// ---------------------------------------------------------------------------
// CrossAttentionBlock: q/k/v proj (bf16 MFMA; K/V rows zeroed where masked) ->
// flash attention (32x32 MFMA, fixed-m softmax, double-buffered DMA staging,
// wave specialization (qsub x kvsub), pure-sum partials) -> merge(+transpose)
// -> o proj (+residual) -> LayerNorm.  B=2,SQ=1024,SKV=4096,E=1024,H=16,D=64.
// Fixed-m softmax: p = 2^(s*log2e/8 - 10). Masked kv have K=V=0 => s==0 =>
// p = 2^-10 exactly; contributes 0 to O and n_masked*2^-10 to l (subtracted).
// R5: never cap launch_bounds below live set.  R6: stage-then-barrier drains
// the DMA (latency exposed).  R7: register-direct chains on L2 latency.
// This round: {barrier; stage(kt+1); compute(kt)} -- DMA issued ~250 cyc
// before its consuming barrier -> latency hidden, ONE barrier per tile.
// ---------------------------------------------------------------------------

typedef __bf16 bf16x8_t  __attribute__((ext_vector_type(8)));
typedef float  f32x4_t   __attribute__((ext_vector_type(4)));
typedef float  f32x16_t  __attribute__((ext_vector_type(16)));

#define E_DIM 1024
#define NH    16
#define HD    64
#define SCALE_L2E 0.1803368804f   // (1/8) * log2(e)
#define FIXM  10.0f

__device__ __forceinline__ unsigned short f32_bf16(float f) {
    union { float f; unsigned int u; } v; v.f = f;
    unsigned int u = v.u;
    unsigned int r = (u + 0x7fffu + ((u >> 16) & 1u)) >> 16;  // RNE
    return (unsigned short)r;
}

__device__ __forceinline__ unsigned pack_bf16(float a, float b) {
    __bf16 x = (__bf16)a, y = (__bf16)b;
    unsigned short ux = __builtin_bit_cast(unsigned short, x);
    unsigned short uy = __builtin_bit_cast(unsigned short, y);
    return (unsigned)ux | ((unsigned)uy << 16);
}

// async global->LDS, 16B per lane; lds base must be wave-uniform
__device__ __forceinline__ void gld16(const unsigned short* g, unsigned short* l) {
    __builtin_amdgcn_global_load_lds(
        (const __attribute__((address_space(1))) unsigned int*)g,
        (__attribute__((address_space(3))) unsigned int*)l, 16, 0, 0);
}

__device__ __forceinline__ bf16x8_t ld16g(const unsigned short* p) {
    union { uint4 u; bf16x8_t f; } v;
    v.u = *reinterpret_cast<const uint4*>(p);
    return v.f;
}

// ---------------- fused fp32 -> bf16 casts (all 6 tensors) -----------------
__global__ void cast_all(const float* __restrict__ q, const float* __restrict__ kv,
                         const float* __restrict__ wq, const float* __restrict__ wk,
                         const float* __restrict__ wv, const float* __restrict__ wo,
                         unsigned short* __restrict__ Xq, unsigned short* __restrict__ Xkv,
                         unsigned short* __restrict__ Wqb, unsigned short* __restrict__ Wkb,
                         unsigned short* __restrict__ Wvb, unsigned short* __restrict__ Wob) {
    long i = (long)blockIdx.x * 256 + threadIdx.x;   // float4 index
    const float* src; unsigned short* dst; long off;
    if (i < 2621440) {
        if (i < 524288) { src = q;  dst = Xq;  off = i; }
        else            { src = kv; dst = Xkv; off = i - 524288; }
    } else {
        long j = i - 2621440;
        int w = (int)(j >> 18); off = j & 262143;
        src = (w == 0) ? wq : (w == 1) ? wk : (w == 2) ? wv : wo;
        dst = (w == 0) ? Wqb : (w == 1) ? Wkb : (w == 2) ? Wvb : Wob;
    }
    float4 v = reinterpret_cast<const float4*>(src)[off];
    ushort4 o;
    o.x = f32_bf16(v.x); o.y = f32_bf16(v.y);
    o.z = f32_bf16(v.z); o.w = f32_bf16(v.w);
    reinterpret_cast<ushort4*>(dst)[off] = o;
}

// ---------------- count masked kv per batch -> n_masked * 2^-10 ------------
__global__ void count_mask(const int* __restrict__ m, float* __restrict__ Sub) {
    __shared__ int red[4];
    int b = blockIdx.x, t = threadIdx.x;
    int s = 0;
#pragma unroll
    for (int k = 0; k < 16; k++) s += (m[b * 4096 + k * 256 + t] != 0);
#pragma unroll
    for (int off = 32; off >= 1; off >>= 1) s += __shfl_xor(s, off, 64);
    if ((t & 63) == 0) red[t >> 6] = s;
    __syncthreads();
    if (t == 0)
        Sub[b] = (float)(4096 - (red[0] + red[1] + red[2] + red[3])) * 0.0009765625f;
}

// ---------------- GEMM: C = A @ W^T + bias (m97-style staging) -------------
// mode 0: [B,H,S,D] (Q, no mask).  mode 1: [B,H,S,D], masked rows zeroed (K).
// mode 2: [B,H,D,S] (V^T), masked cols zeroed.
#define BM 128
#define BN 128
#define BK 64

__global__ __launch_bounds__(256) void gemm_qkv(
    const unsigned short* __restrict__ A,
    const unsigned short* __restrict__ W,
    const float* __restrict__ bias,
    unsigned short* __restrict__ out,
    int lgS, int mode, const int* __restrict__ kvm)
{
    __shared__ __align__(16) unsigned short As[BM * BK];
    __shared__ __align__(16) unsigned short Bs[BN * BK];
    int tid  = threadIdx.x;
    int m0   = blockIdx.y * BM;
    int n0   = blockIdx.x * BN;
    int lane = tid & 63;
    int wvu  = __builtin_amdgcn_readfirstlane(tid >> 6);
    int l15  = lane & 15, quad = lane >> 4, x7 = l15 & 7;
    int wm   = ((tid >> 6) >> 1) * 64, wn = ((tid >> 6) & 1) * 64;

    f32x4_t acc[4][4];
#pragma unroll
    for (int i = 0; i < 4; i++)
#pragma unroll
        for (int j = 0; j < 4; j++) acc[i][j] = (f32x4_t)(0.f);

    for (int k0 = 0; k0 < 1024; k0 += BK) {
        __syncthreads();
#pragma unroll
        for (int i = 0; i < 4; i++) {
            int s = (i * 4 + wvu) * 64 + lane;
            int row = s >> 3, pcol = ((s & 7) ^ (row & 7)) << 3;
            gld16(&A[(long)(m0 + row) * 1024 + k0 + pcol], &As[(i * 4 + wvu) * 512]);
            gld16(&W[(long)(n0 + row) * 1024 + k0 + pcol], &Bs[(i * 4 + wvu) * 512]);
        }
        __syncthreads();
        const char* Ab = (const char*)As;
        const char* Bb = (const char*)Bs;
#pragma unroll
        for (int ks = 0; ks < 2; ks++) {
            int pos = (((ks << 2) + quad) ^ x7) << 4;
            bf16x8_t af[4], bf[4];
#pragma unroll
            for (int mi = 0; mi < 4; mi++)
                af[mi] = *reinterpret_cast<const bf16x8_t*>(
                    Ab + (wm + mi * 16 + l15) * 128 + pos);
#pragma unroll
            for (int ni = 0; ni < 4; ni++)
                bf[ni] = *reinterpret_cast<const bf16x8_t*>(
                    Bb + (wn + ni * 16 + l15) * 128 + pos);
#pragma unroll
            for (int mi = 0; mi < 4; mi++)
#pragma unroll
                for (int ni = 0; ni < 4; ni++)
                    acc[mi][ni] = __builtin_amdgcn_mfma_f32_16x16x32_bf16(
                        af[mi], bf[ni], acc[mi][ni], 0, 0, 0);
        }
    }
    int Smask = (1 << lgS) - 1;
    if (mode == 0) {
#pragma unroll
        for (int mi = 0; mi < 4; mi++)
#pragma unroll
            for (int ni = 0; ni < 4; ni++) {
                int n = n0 + wn + ni * 16 + l15;
                float bv = bias[n];
                int h = n >> 6, d = n & 63;
#pragma unroll
                for (int r = 0; r < 4; r++) {
                    int mg = m0 + wm + mi * 16 + quad * 4 + r;
                    int b = mg >> lgS, s = mg & Smask;
                    out[(((b * NH + h) << lgS) + s) * HD + d] =
                        f32_bf16(acc[mi][ni][r] + bv);
                }
            }
    } else if (mode == 1) {
#pragma unroll
        for (int mi = 0; mi < 4; mi++)
#pragma unroll
            for (int ni = 0; ni < 4; ni++) {
                int n = n0 + wn + ni * 16 + l15;
                float bv = bias[n];
                int h = n >> 6, d = n & 63;
#pragma unroll
                for (int r = 0; r < 4; r++) {
                    int mg = m0 + wm + mi * 16 + quad * 4 + r;
                    int b = mg >> lgS, s = mg & Smask;
                    unsigned short val = kvm[(b << lgS) + s]
                        ? f32_bf16(acc[mi][ni][r] + bv) : (unsigned short)0;
                    out[(((b * NH + h) << lgS) + s) * HD + d] = val;
                }
            }
    } else {
#pragma unroll
        for (int mi = 0; mi < 4; mi++)
#pragma unroll
            for (int ni = 0; ni < 4; ni++) {
                int n = n0 + wn + ni * 16 + l15;
                float bv = bias[n];
                int h = n >> 6, d = n & 63;
                int mg0 = m0 + wm + mi * 16 + quad * 4;
                int b = mg0 >> lgS, s = mg0 & Smask;
                int4 mk = *reinterpret_cast<const int4*>(&kvm[(b << lgS) + s]);
                ushort4 w;
                w.x = mk.x ? f32_bf16(acc[mi][ni][0] + bv) : (unsigned short)0;
                w.y = mk.y ? f32_bf16(acc[mi][ni][1] + bv) : (unsigned short)0;
                w.z = mk.z ? f32_bf16(acc[mi][ni][2] + bv) : (unsigned short)0;
                w.w = mk.w ? f32_bf16(acc[mi][ni][3] + bv) : (unsigned short)0;
                *reinterpret_cast<ushort4*>(
                    &out[(((b * NH + h) * HD + d) << lgS) + s]) = w;
            }
    }
}

// ---------------- O-proj GEMM + bias + residual -> fp32 --------------------
__global__ __launch_bounds__(256) void gemm_oproj(
    const unsigned short* __restrict__ A,
    const unsigned short* __restrict__ W,
    const float* __restrict__ bias,
    const float* __restrict__ resid,
    float* __restrict__ xout)
{
    __shared__ __align__(16) unsigned short As[BM * BK];
    __shared__ __align__(16) unsigned short Bs[BN * BK];
    int tid  = threadIdx.x;
    int m0   = blockIdx.y * BM;
    int n0   = blockIdx.x * BN;
    int lane = tid & 63;
    int wvu  = __builtin_amdgcn_readfirstlane(tid >> 6);
    int l15  = lane & 15, quad = lane >> 4, x7 = l15 & 7;
    int wm   = ((tid >> 6) >> 1) * 64, wn = ((tid >> 6) & 1) * 64;

    f32x4_t acc[4][4];
#pragma unroll
    for (int i = 0; i < 4; i++)
#pragma unroll
        for (int j = 0; j < 4; j++) acc[i][j] = (f32x4_t)(0.f);

    for (int k0 = 0; k0 < 1024; k0 += BK) {
        __syncthreads();
#pragma unroll
        for (int i = 0; i < 4; i++) {
            int s = (i * 4 + wvu) * 64 + lane;
            int row = s >> 3, pcol = ((s & 7) ^ (row & 7)) << 3;
            gld16(&A[(long)(m0 + row) * 1024 + k0 + pcol], &As[(i * 4 + wvu) * 512]);
            gld16(&W[(long)(n0 + row) * 1024 + k0 + pcol], &Bs[(i * 4 + wvu) * 512]);
        }
        __syncthreads();
        const char* Ab = (const char*)As;
        const char* Bb = (const char*)Bs;
#pragma unroll
        for (int ks = 0; ks < 2; ks++) {
            int pos = (((ks << 2) + quad) ^ x7) << 4;
            bf16x8_t af[4], bf[4];
#pragma unroll
            for (int mi = 0; mi < 4; mi++)
                af[mi] = *reinterpret_cast<const bf16x8_t*>(
                    Ab + (wm + mi * 16 + l15) * 128 + pos);
#pragma unroll
            for (int ni = 0; ni < 4; ni++)
                bf[ni] = *reinterpret_cast<const bf16x8_t*>(
                    Bb + (wn + ni * 16 + l15) * 128 + pos);
#pragma unroll
            for (int mi = 0; mi < 4; mi++)
#pragma unroll
                for (int ni = 0; ni < 4; ni++)
                    acc[mi][ni] = __builtin_amdgcn_mfma_f32_16x16x32_bf16(
                        af[mi], bf[ni], acc[mi][ni], 0, 0, 0);
        }
    }
#pragma unroll
    for (int mi = 0; mi < 4; mi++)
#pragma unroll
        for (int ni = 0; ni < 4; ni++) {
            int n = n0 + wn + ni * 16 + l15;
            float bv = bias[n];
#pragma unroll
            for (int r = 0; r < 4; r++) {
                int mg = m0 + wm + mi * 16 + quad * 4 + r;
                xout[mg * 1024 + n] = acc[mi][ni][r] + bv + resid[mg * 1024 + n];
            }
        }
}

// ---------------- flash attention: double-buffered DMA, 64-kv tiles --------
// grid 1024 blocks of 256 (4 waves).  Block = 64 q of one (b,h) x kv-half
// (2048, 32 tiles of 64).  Wave w: qsub = w&1 (32 q), kvsub = w>>1 (32 kv of
// each tile).  Loop: { barrier; stage(kt+1)->other buf; compute(kt) } -- one
// barrier/tile, DMA issued a full compute-phase before its consuming barrier.
// Partial index p = bhalf*2 + kvsub (4 partials per (bh,q), pure sums).
__global__ __launch_bounds__(256, 3) void attn_kernel(
    const unsigned short* __restrict__ Q,   // [B,NH,1024,64]
    const unsigned short* __restrict__ K,   // [B,NH,4096,64]  masked rows = 0
    const unsigned short* __restrict__ VT,  // [B,NH,64,4096]  masked cols = 0
    float* __restrict__ Osc,                // [4][32][64][1024] fp32 partial O^T
    float* __restrict__ Lsc)                // [4][32][1024] partial l
{
    __shared__ __align__(16) unsigned short Kbuf[2][64 * 64];
    __shared__ __align__(16) unsigned short Vbuf[2][64 * 64];

    int tid  = threadIdx.x;
    int lane = tid & 63;
    int w    = tid >> 6;
    int wvu  = __builtin_amdgcn_readfirstlane(w);
    int l31  = lane & 31, hw = lane >> 5;
    int qsub = w & 1, kvsub = w >> 1;

    // XCD-grouped: 4 (b,h) per XCD; q-tiles and halves of one bh share L2
    int bid  = blockIdx.x;
    int xcd  = bid & 7, gidx = bid >> 3;
    int bh   = xcd * 4 + (gidx & 3);
    int rest = gidx >> 2;                    // 0..31
    int q0   = (rest & 15) * 64;
    int bhalf = rest >> 4;

    const unsigned short* Kb = K + ((long)bh * 4096 + bhalf * 2048) * HD;
    const unsigned short* Vb = VT + (long)bh * HD * 4096 + bhalf * 2048;
    const unsigned short* Qb = Q + ((long)bh * 1024 + q0) * HD;

    // Q fragments (B-operand): B[n=q=l31][k=hw*8+j], 4 k-chunks of 16
    bf16x8_t qfr[4];
#pragma unroll
    for (int ks = 0; ks < 4; ks++)
        qfr[ks] = ld16g(Qb + (qsub * 32 + l31) * HD + ks * 16 + hw * 8);

    f32x16_t oacc[2];
    oacc[0] = (f32x16_t)(0.f); oacc[1] = (f32x16_t)(0.f);
    float l_run = 0.f;

    // stage tile kt (64 kv x 64 d for K; 64 d x 64 kv for V^T) into buf
    auto stage = [&](int kt, int bufi) {
#pragma unroll
        for (int i = 0; i < 2; i++) {
            int s = (i * 4 + wvu) * 64 + lane;            // 0..511 slots of 16B
            int row = s >> 3, pc = ((s & 7) ^ (row & 7)) << 3;
            gld16(&Kb[(long)(kt * 64 + row) * HD + pc], &Kbuf[bufi][(i * 4 + wvu) * 512]);
            gld16(&Vb[(long)row * 4096 + kt * 64 + pc], &Vbuf[bufi][(i * 4 + wvu) * 512]);
        }
    };

    const char* Kc = (const char*)Kbuf;
    const char* Vc = (const char*)Vbuf;

    stage(0, 0);
#pragma unroll 2
    for (int kt = 0; kt < 32; kt++) {
        __syncthreads();                 // stage(kt) visible; compute(kt-1) done
        if (kt + 1 < 32) stage(kt + 1, (kt + 1) & 1);
        int bo = (kt & 1) * 8192;        // byte offset of current buffer

        // ---- S^T: C[kv32][q32], kv rows = kvsub*32 + l31 ----
        f32x16_t sa = (f32x16_t)(0.f);
        int krow = kvsub * 32 + l31;
#pragma unroll
        for (int ks = 0; ks < 4; ks++) {
            int phys = (ks * 2 + hw) ^ (krow & 7);
            bf16x8_t kf = *reinterpret_cast<const bf16x8_t*>(
                Kc + bo + krow * 128 + phys * 16);
            sa = __builtin_amdgcn_mfma_f32_32x32x16_bf16(kf, qfr[ks], sa, 0, 0, 0);
        }

        // ---- fixed-m softmax: p = 2^(s*c - 10) ----
        float pv[16];
        float rs = 0.f;
#pragma unroll
        for (int r = 0; r < 16; r++) {
            pv[r] = exp2f(fmaf(sa[r], SCALE_L2E, -FIXM));
            rs += pv[r];
        }
        l_run += rs;
        unsigned pku[8];
#pragma unroll
        for (int s4 = 0; s4 < 4; s4++) {
            pku[s4 * 2 + 0] = pack_bf16(pv[s4 * 4 + 0], pv[s4 * 4 + 1]);
            pku[s4 * 2 + 1] = pack_bf16(pv[s4 * 4 + 2], pv[s4 * 4 + 3]);
        }

        // ---- PV: O^T[d][q] += V^T · P over the wave's 32-kv strip ----
#pragma unroll
        for (int ks2 = 0; ks2 < 2; ks2++) {
            int s_lo = ks2 * 2, s_own = ks2 * 2 + hw;
            unsigned send0 = hw ? pku[s_lo * 2 + 0] : pku[(s_lo + 1) * 2 + 0];
            unsigned send1 = hw ? pku[s_lo * 2 + 1] : pku[(s_lo + 1) * 2 + 1];
            unsigned recv0 = __shfl_xor((int)send0, 32, 64);
            unsigned recv1 = __shfl_xor((int)send1, 32, 64);
            union { uint4 u; bf16x8_t f; } bw;
            bw.u.x = hw ? recv0 : pku[s_own * 2 + 0];
            bw.u.y = hw ? recv1 : pku[s_own * 2 + 1];
            bw.u.z = hw ? pku[s_own * 2 + 0] : recv0;
            bw.u.w = hw ? pku[s_own * 2 + 1] : recv1;
            int c = kvsub * 4 + ks2 * 2 + hw;            // kv 8-chunk index
#pragma unroll
            for (int ds = 0; ds < 2; ds++) {
                int vrow = ds * 32 + l31;
                int phys = c ^ (vrow & 7);
                bf16x8_t va = *reinterpret_cast<const bf16x8_t*>(
                    Vc + bo + vrow * 128 + phys * 16);
                oacc[ds] = __builtin_amdgcn_mfma_f32_32x32x16_bf16(
                    va, bw.f, oacc[ds], 0, 0, 0);
            }
        }
    }

    // ---- epilogue: per-wave partial, coalesced [d][q] stores ----
    l_run += __shfl_xor(l_run, 32, 64);
    int p = bhalf * 2 + kvsub;
    int q = q0 + qsub * 32 + l31;
    if (hw == 0)
        Lsc[((long)p * 32 + bh) * 1024 + q] = l_run;
    long obase = (((long)p * 32 + bh) * 64) * 1024;
#pragma unroll
    for (int ds = 0; ds < 2; ds++)
#pragma unroll
        for (int r = 0; r < 16; r++) {
            int d = ds * 32 + (r & 3) + 8 * (r >> 2) + 4 * hw;
            Osc[obase + (long)d * 1024 + q] = oacc[ds][r];
        }
}

// ---------------- merge 4 partials, normalize, transpose to AO -------------
__global__ __launch_bounds__(256) void attn_merge(
    const float* __restrict__ Osc, const float* __restrict__ Lsc,
    const float* __restrict__ Sub, unsigned short* __restrict__ AO)
{
    __shared__ unsigned short T[64 * 66];
    int t = threadIdx.x, w = t >> 6, lane = t & 63;
    int bh = blockIdx.y, b = bh >> 4, h = bh & 15;
    int q0 = blockIdx.x * 64;
    int q = q0 + lane;

    float ls = Lsc[(long)(0 * 32 + bh) * 1024 + q]
             + Lsc[(long)(1 * 32 + bh) * 1024 + q]
             + Lsc[(long)(2 * 32 + bh) * 1024 + q]
             + Lsc[(long)(3 * 32 + bh) * 1024 + q] - Sub[b];
    float inv = __builtin_amdgcn_rcpf(ls);
    inv = inv * (2.f - ls * inv);            // NR refine

#pragma unroll
    for (int dd = 0; dd < 16; dd++) {
        int d = w * 16 + dd;
        long base = (long)bh * 64 * 1024 + (long)d * 1024 + q;
        float o = Osc[base]
                + Osc[base + 32l * 64 * 1024]
                + Osc[base + 64l * 64 * 1024]
                + Osc[base + 96l * 64 * 1024];
        T[lane * 66 + d] = f32_bf16(o * inv);
    }
    __syncthreads();
    int q2 = t >> 2, c16 = (t & 3) * 16;
    unsigned ov[8];
#pragma unroll
    for (int j = 0; j < 8; j++)
        ov[j] = *reinterpret_cast<const unsigned*>(&T[q2 * 66 + c16 + j * 2]);
    unsigned short* dst = &AO[((long)(b * 1024 + q0 + q2)) * E_DIM + h * HD + c16];
    reinterpret_cast<uint4*>(dst)[0] = make_uint4(ov[0], ov[1], ov[2], ov[3]);
    reinterpret_cast<uint4*>(dst)[1] = make_uint4(ov[4], ov[5], ov[6], ov[7]);
}

// ---------------- LayerNorm over E=1024 ------------------------------------
__global__ __launch_bounds__(256) void ln_kernel(
    const float* __restrict__ x, const float* __restrict__ g,
    const float* __restrict__ be, float* __restrict__ out)
{
    __shared__ float red[8];
    int row = blockIdx.x, tid = threadIdx.x;
    float4 v = reinterpret_cast<const float4*>(x)[row * 256 + tid];
    float s  = v.x + v.y + v.z + v.w;
    float sq = v.x * v.x + v.y * v.y + v.z * v.z + v.w * v.w;
#pragma unroll
    for (int off = 32; off >= 1; off >>= 1) {
        s  += __shfl_xor(s,  off, 64);
        sq += __shfl_xor(sq, off, 64);
    }
    if ((tid & 63) == 0) { red[tid >> 6] = s; red[4 + (tid >> 6)] = sq; }
    __syncthreads();
    s  = red[0] + red[1] + red[2] + red[3];
    sq = red[4] + red[5] + red[6] + red[7];
    float mu  = s * (1.f / 1024.f);
    float var = sq * (1.f / 1024.f) - mu * mu;
    float rs  = rsqrtf(var + 1e-5f);
    int c = tid * 4;
    float4 o;
    o.x = (v.x - mu) * rs * g[c]     + be[c];
    o.y = (v.y - mu) * rs * g[c + 1] + be[c + 1];
    o.z = (v.z - mu) * rs * g[c + 2] + be[c + 2];
    o.w = (v.w - mu) * rs * g[c + 3] + be[c + 3];
    reinterpret_cast<float4*>(out)[row * 256 + tid] = o;
}

// ---------------------------------------------------------------------------
extern "C" void kernel_launch(void* const* d_in, const int* in_sizes, int n_in,
                              void* d_out, int out_size, void* d_ws, size_t ws_size,
                              hipStream_t stream) {
    const float* query     = (const float*)d_in[0];
    const float* key_value = (const float*)d_in[1];
    const int*   kv_mask   = (const int*)d_in[2];
    const float* Wq = (const float*)d_in[3];
    const float* bq = (const float*)d_in[4];
    const float* Wk = (const float*)d_in[5];
    const float* bk = (const float*)d_in[6];
    const float* Wv = (const float*)d_in[7];
    const float* bv = (const float*)d_in[8];
    const float* Wo = (const float*)d_in[9];
    const float* bo = (const float*)d_in[10];
    const float* ln_g = (const float*)d_in[11];
    const float* ln_b = (const float*)d_in[12];
    float* out = (float*)d_out;

    // workspace layout (MiB). Osc (32 MB) overlays the cast buffers, which
    // are dead before attn_kernel runs (stream-ordered).
    char* ws = (char*)d_ws;
    unsigned short* Xq  = (unsigned short*)(ws);                     // 0-4
    unsigned short* Xkv = (unsigned short*)(ws + (4ll  << 20));      // 4-20
    unsigned short* Wqb = (unsigned short*)(ws + (20ll << 20));      // 20-22
    unsigned short* Wkb = (unsigned short*)(ws + (22ll << 20));      // 22-24
    unsigned short* Wvb = (unsigned short*)(ws + (24ll << 20));      // 24-26
    float*          Osc = (float*)(ws);                              // 0-32 (after gemms)
    unsigned short* Kh  = (unsigned short*)(ws + (32ll << 20));      // 32-48
    unsigned short* VTh = (unsigned short*)(ws + (48ll << 20));      // 48-64
    unsigned short* AO  = (unsigned short*)(ws + (64ll << 20));      // 64-68
    float*          Xr  = (float*)(ws + (68ll << 20));               // 68-76
    float*          Lsc = (float*)(ws + (76ll << 20));               // 76-76.5
    float*          Sub = (float*)(ws + (77ll << 20));               // tiny
    unsigned short* Qh  = (unsigned short*)(ws + (80ll << 20));      // 80-84
    unsigned short* Wob = (unsigned short*)(ws + (84ll << 20));      // 84-86

    cast_all<<<14336, 256, 0, stream>>>(query, key_value, Wq, Wk, Wv, Wo,
                                        Xq, Xkv, Wqb, Wkb, Wvb, Wob);
    count_mask<<<2, 256, 0, stream>>>(kv_mask, Sub);

    gemm_qkv<<<dim3(8, 16), 256, 0, stream>>>(Xq,  Wqb, bq, Qh,  10, 0, kv_mask);
    gemm_qkv<<<dim3(8, 64), 256, 0, stream>>>(Xkv, Wkb, bk, Kh,  12, 1, kv_mask);
    gemm_qkv<<<dim3(8, 64), 256, 0, stream>>>(Xkv, Wvb, bv, VTh, 12, 2, kv_mask);

    attn_kernel<<<1024, 256, 0, stream>>>(Qh, Kh, VTh, Osc, Lsc);
    attn_merge<<<dim3(16, 32), 256, 0, stream>>>(Osc, Lsc, Sub, AO);

    gemm_oproj<<<dim3(8, 16), 256, 0, stream>>>(AO, Wob, bo, query, Xr);

    ln_kernel<<<2048, 256, 0, stream>>>(Xr, ln_g, ln_b, out);
}

// Round 9
// 280.490 us; speedup vs baseline: 1.3495x; 1.0659x over previous
//
#include <hip/hip_runtime.h>
#include <cstdint>

// ---------------------------------------------------------------------------
// CrossAttentionBlock: q/k/v proj (bf16 MFMA; K/V rows zeroed where masked) ->
// flash attention (32x32 MFMA, fixed-m softmax, double-buffered DMA staging,
// wave specialization qsub x kvsub, in-block kvsub merge, pure-sum partials)
// -> merge(+transpose) -> o proj (+residual) -> LayerNorm.
// B=2,SQ=1024,SKV=4096,E=1024,H=16,D=64.
// Fixed-m softmax: p = 2^(s*log2e/8 - 10). Masked kv have K=V=0 => s==0 =>
// p = 2^-10 exactly; contributes 0 to O and n_masked*2^-10 to l (subtracted).
// R5: never cap launch_bounds below live set (spill).  R6: stage-then-barrier
// drains DMA.  R7: register-direct chains on L2 latency.  R8: {barrier;
// stage(kt+1); compute(kt)} hides DMA with one barrier/tile -> 85us.
// R9: live set ~102 unified regs -> (256,4) fits; in-block kvsub merge.
// ---------------------------------------------------------------------------

typedef __bf16 bf16x8_t  __attribute__((ext_vector_type(8)));
typedef float  f32x4_t   __attribute__((ext_vector_type(4)));
typedef float  f32x16_t  __attribute__((ext_vector_type(16)));

#define E_DIM 1024
#define NH    16
#define HD    64
#define SCALE_L2E 0.1803368804f   // (1/8) * log2(e)
#define FIXM  10.0f

__device__ __forceinline__ unsigned short f32_bf16(float f) {
    union { float f; unsigned int u; } v; v.f = f;
    unsigned int u = v.u;
    unsigned int r = (u + 0x7fffu + ((u >> 16) & 1u)) >> 16;  // RNE
    return (unsigned short)r;
}

__device__ __forceinline__ unsigned pack_bf16(float a, float b) {
    __bf16 x = (__bf16)a, y = (__bf16)b;
    unsigned short ux = __builtin_bit_cast(unsigned short, x);
    unsigned short uy = __builtin_bit_cast(unsigned short, y);
    return (unsigned)ux | ((unsigned)uy << 16);
}

// async global->LDS, 16B per lane; lds base must be wave-uniform
__device__ __forceinline__ void gld16(const unsigned short* g, unsigned short* l) {
    __builtin_amdgcn_global_load_lds(
        (const __attribute__((address_space(1))) unsigned int*)g,
        (__attribute__((address_space(3))) unsigned int*)l, 16, 0, 0);
}

__device__ __forceinline__ bf16x8_t ld16g(const unsigned short* p) {
    union { uint4 u; bf16x8_t f; } v;
    v.u = *reinterpret_cast<const uint4*>(p);
    return v.f;
}

// ------- fused fp32 -> bf16 casts (all 6 tensors) + mask count -------------
__global__ void cast_all(const float* __restrict__ q, const float* __restrict__ kv,
                         const float* __restrict__ wq, const float* __restrict__ wk,
                         const float* __restrict__ wv, const float* __restrict__ wo,
                         unsigned short* __restrict__ Xq, unsigned short* __restrict__ Xkv,
                         unsigned short* __restrict__ Wqb, unsigned short* __restrict__ Wkb,
                         unsigned short* __restrict__ Wvb, unsigned short* __restrict__ Wob,
                         const int* __restrict__ msk, float* __restrict__ Sub) {
    __shared__ int red[4];
    if (blockIdx.x >= 14336) {           // mask-count blocks (b = 0,1)
        int b = blockIdx.x - 14336, t = threadIdx.x;
        int s = 0;
#pragma unroll
        for (int k = 0; k < 16; k++) s += (msk[b * 4096 + k * 256 + t] != 0);
#pragma unroll
        for (int off = 32; off >= 1; off >>= 1) s += __shfl_xor(s, off, 64);
        if ((t & 63) == 0) red[t >> 6] = s;
        __syncthreads();
        if (t == 0)
            Sub[b] = (float)(4096 - (red[0] + red[1] + red[2] + red[3])) * 0.0009765625f;
        return;
    }
    long i = (long)blockIdx.x * 256 + threadIdx.x;   // float4 index
    const float* src; unsigned short* dst; long off;
    if (i < 2621440) {
        if (i < 524288) { src = q;  dst = Xq;  off = i; }
        else            { src = kv; dst = Xkv; off = i - 524288; }
    } else {
        long j = i - 2621440;
        int w = (int)(j >> 18); off = j & 262143;
        src = (w == 0) ? wq : (w == 1) ? wk : (w == 2) ? wv : wo;
        dst = (w == 0) ? Wqb : (w == 1) ? Wkb : (w == 2) ? Wvb : Wob;
    }
    float4 v = reinterpret_cast<const float4*>(src)[off];
    ushort4 o;
    o.x = f32_bf16(v.x); o.y = f32_bf16(v.y);
    o.z = f32_bf16(v.z); o.w = f32_bf16(v.w);
    reinterpret_cast<ushort4*>(dst)[off] = o;
}

// ---------------- GEMM bodies (m97-style staging) --------------------------
#define BM 128
#define BN 128
#define BK 64

// Q projection: out [B,H,S,D], lgS=10, no mask
__global__ __launch_bounds__(256) void gemm_q(
    const unsigned short* __restrict__ A,
    const unsigned short* __restrict__ W,
    const float* __restrict__ bias,
    unsigned short* __restrict__ out)
{
    __shared__ __align__(16) unsigned short As[BM * BK];
    __shared__ __align__(16) unsigned short Bs[BN * BK];
    int tid  = threadIdx.x;
    int m0   = blockIdx.y * BM;
    int n0   = blockIdx.x * BN;
    int lane = tid & 63;
    int wvu  = __builtin_amdgcn_readfirstlane(tid >> 6);
    int l15  = lane & 15, quad = lane >> 4, x7 = l15 & 7;
    int wm   = ((tid >> 6) >> 1) * 64, wn = ((tid >> 6) & 1) * 64;

    f32x4_t acc[4][4];
#pragma unroll
    for (int i = 0; i < 4; i++)
#pragma unroll
        for (int j = 0; j < 4; j++) acc[i][j] = (f32x4_t)(0.f);

    for (int k0 = 0; k0 < 1024; k0 += BK) {
        __syncthreads();
#pragma unroll
        for (int i = 0; i < 4; i++) {
            int s = (i * 4 + wvu) * 64 + lane;
            int row = s >> 3, pcol = ((s & 7) ^ (row & 7)) << 3;
            gld16(&A[(long)(m0 + row) * 1024 + k0 + pcol], &As[(i * 4 + wvu) * 512]);
            gld16(&W[(long)(n0 + row) * 1024 + k0 + pcol], &Bs[(i * 4 + wvu) * 512]);
        }
        __syncthreads();
        const char* Ab = (const char*)As;
        const char* Bb = (const char*)Bs;
#pragma unroll
        for (int ks = 0; ks < 2; ks++) {
            int pos = (((ks << 2) + quad) ^ x7) << 4;
            bf16x8_t af[4], bf[4];
#pragma unroll
            for (int mi = 0; mi < 4; mi++)
                af[mi] = *reinterpret_cast<const bf16x8_t*>(
                    Ab + (wm + mi * 16 + l15) * 128 + pos);
#pragma unroll
            for (int ni = 0; ni < 4; ni++)
                bf[ni] = *reinterpret_cast<const bf16x8_t*>(
                    Bb + (wn + ni * 16 + l15) * 128 + pos);
#pragma unroll
            for (int mi = 0; mi < 4; mi++)
#pragma unroll
                for (int ni = 0; ni < 4; ni++)
                    acc[mi][ni] = __builtin_amdgcn_mfma_f32_16x16x32_bf16(
                        af[mi], bf[ni], acc[mi][ni], 0, 0, 0);
        }
    }
#pragma unroll
    for (int mi = 0; mi < 4; mi++)
#pragma unroll
        for (int ni = 0; ni < 4; ni++) {
            int n = n0 + wn + ni * 16 + l15;
            float bv = bias[n];
            int h = n >> 6, d = n & 63;
#pragma unroll
            for (int r = 0; r < 4; r++) {
                int mg = m0 + wm + mi * 16 + quad * 4 + r;
                int b = mg >> 10, s = mg & 1023;
                out[(((b * NH + h) << 10) + s) * HD + d] =
                    f32_bf16(acc[mi][ni][r] + bv);
            }
        }
}

// K + V^T projections fused: grid (16,64); bx<8 -> K [B,H,S,D] masked-row-0,
// bx>=8 -> V^T [B,H,D,S] masked-col-0.
__global__ __launch_bounds__(256) void gemm_kv(
    const unsigned short* __restrict__ A,
    const unsigned short* __restrict__ Wk,
    const unsigned short* __restrict__ Wv,
    const float* __restrict__ bk,
    const float* __restrict__ bv,
    unsigned short* __restrict__ Kout,
    unsigned short* __restrict__ Vout,
    const int* __restrict__ kvm)
{
    __shared__ __align__(16) unsigned short As[BM * BK];
    __shared__ __align__(16) unsigned short Bs[BN * BK];
    int tid  = threadIdx.x;
    int bx   = blockIdx.x;
    int isV  = bx >= 8;
    int m0   = blockIdx.y * BM;
    int n0   = (bx & 7) * BN;
    const unsigned short* W = isV ? Wv : Wk;
    const float* bias = isV ? bv : bk;
    int lane = tid & 63;
    int wvu  = __builtin_amdgcn_readfirstlane(tid >> 6);
    int l15  = lane & 15, quad = lane >> 4, x7 = l15 & 7;
    int wm   = ((tid >> 6) >> 1) * 64, wn = ((tid >> 6) & 1) * 64;

    f32x4_t acc[4][4];
#pragma unroll
    for (int i = 0; i < 4; i++)
#pragma unroll
        for (int j = 0; j < 4; j++) acc[i][j] = (f32x4_t)(0.f);

    for (int k0 = 0; k0 < 1024; k0 += BK) {
        __syncthreads();
#pragma unroll
        for (int i = 0; i < 4; i++) {
            int s = (i * 4 + wvu) * 64 + lane;
            int row = s >> 3, pcol = ((s & 7) ^ (row & 7)) << 3;
            gld16(&A[(long)(m0 + row) * 1024 + k0 + pcol], &As[(i * 4 + wvu) * 512]);
            gld16(&W[(long)(n0 + row) * 1024 + k0 + pcol], &Bs[(i * 4 + wvu) * 512]);
        }
        __syncthreads();
        const char* Ab = (const char*)As;
        const char* Bb = (const char*)Bs;
#pragma unroll
        for (int ks = 0; ks < 2; ks++) {
            int pos = (((ks << 2) + quad) ^ x7) << 4;
            bf16x8_t af[4], bf[4];
#pragma unroll
            for (int mi = 0; mi < 4; mi++)
                af[mi] = *reinterpret_cast<const bf16x8_t*>(
                    Ab + (wm + mi * 16 + l15) * 128 + pos);
#pragma unroll
            for (int ni = 0; ni < 4; ni++)
                bf[ni] = *reinterpret_cast<const bf16x8_t*>(
                    Bb + (wn + ni * 16 + l15) * 128 + pos);
#pragma unroll
            for (int mi = 0; mi < 4; mi++)
#pragma unroll
                for (int ni = 0; ni < 4; ni++)
                    acc[mi][ni] = __builtin_amdgcn_mfma_f32_16x16x32_bf16(
                        af[mi], bf[ni], acc[mi][ni], 0, 0, 0);
        }
    }
    if (!isV) {
#pragma unroll
        for (int mi = 0; mi < 4; mi++)
#pragma unroll
            for (int ni = 0; ni < 4; ni++) {
                int n = n0 + wn + ni * 16 + l15;
                float bvv = bias[n];
                int h = n >> 6, d = n & 63;
#pragma unroll
                for (int r = 0; r < 4; r++) {
                    int mg = m0 + wm + mi * 16 + quad * 4 + r;
                    int b = mg >> 12, s = mg & 4095;
                    unsigned short val = kvm[(b << 12) + s]
                        ? f32_bf16(acc[mi][ni][r] + bvv) : (unsigned short)0;
                    Kout[(((b * NH + h) << 12) + s) * HD + d] = val;
                }
            }
    } else {
#pragma unroll
        for (int mi = 0; mi < 4; mi++)
#pragma unroll
            for (int ni = 0; ni < 4; ni++) {
                int n = n0 + wn + ni * 16 + l15;
                float bvv = bias[n];
                int h = n >> 6, d = n & 63;
                int mg0 = m0 + wm + mi * 16 + quad * 4;
                int b = mg0 >> 12, s = mg0 & 4095;
                int4 mk = *reinterpret_cast<const int4*>(&kvm[(b << 12) + s]);
                ushort4 w;
                w.x = mk.x ? f32_bf16(acc[mi][ni][0] + bvv) : (unsigned short)0;
                w.y = mk.y ? f32_bf16(acc[mi][ni][1] + bvv) : (unsigned short)0;
                w.z = mk.z ? f32_bf16(acc[mi][ni][2] + bvv) : (unsigned short)0;
                w.w = mk.w ? f32_bf16(acc[mi][ni][3] + bvv) : (unsigned short)0;
                *reinterpret_cast<ushort4*>(
                    &Vout[(((b * NH + h) * HD + d) << 12) + s]) = w;
            }
    }
}

// ---------------- O-proj GEMM + bias + residual -> fp32 --------------------
__global__ __launch_bounds__(256) void gemm_oproj(
    const unsigned short* __restrict__ A,
    const unsigned short* __restrict__ W,
    const float* __restrict__ bias,
    const float* __restrict__ resid,
    float* __restrict__ xout)
{
    __shared__ __align__(16) unsigned short As[BM * BK];
    __shared__ __align__(16) unsigned short Bs[BN * BK];
    int tid  = threadIdx.x;
    int m0   = blockIdx.y * BM;
    int n0   = blockIdx.x * BN;
    int lane = tid & 63;
    int wvu  = __builtin_amdgcn_readfirstlane(tid >> 6);
    int l15  = lane & 15, quad = lane >> 4, x7 = l15 & 7;
    int wm   = ((tid >> 6) >> 1) * 64, wn = ((tid >> 6) & 1) * 64;

    f32x4_t acc[4][4];
#pragma unroll
    for (int i = 0; i < 4; i++)
#pragma unroll
        for (int j = 0; j < 4; j++) acc[i][j] = (f32x4_t)(0.f);

    for (int k0 = 0; k0 < 1024; k0 += BK) {
        __syncthreads();
#pragma unroll
        for (int i = 0; i < 4; i++) {
            int s = (i * 4 + wvu) * 64 + lane;
            int row = s >> 3, pcol = ((s & 7) ^ (row & 7)) << 3;
            gld16(&A[(long)(m0 + row) * 1024 + k0 + pcol], &As[(i * 4 + wvu) * 512]);
            gld16(&W[(long)(n0 + row) * 1024 + k0 + pcol], &Bs[(i * 4 + wvu) * 512]);
        }
        __syncthreads();
        const char* Ab = (const char*)As;
        const char* Bb = (const char*)Bs;
#pragma unroll
        for (int ks = 0; ks < 2; ks++) {
            int pos = (((ks << 2) + quad) ^ x7) << 4;
            bf16x8_t af[4], bf[4];
#pragma unroll
            for (int mi = 0; mi < 4; mi++)
                af[mi] = *reinterpret_cast<const bf16x8_t*>(
                    Ab + (wm + mi * 16 + l15) * 128 + pos);
#pragma unroll
            for (int ni = 0; ni < 4; ni++)
                bf[ni] = *reinterpret_cast<const bf16x8_t*>(
                    Bb + (wn + ni * 16 + l15) * 128 + pos);
#pragma unroll
            for (int mi = 0; mi < 4; mi++)
#pragma unroll
                for (int ni = 0; ni < 4; ni++)
                    acc[mi][ni] = __builtin_amdgcn_mfma_f32_16x16x32_bf16(
                        af[mi], bf[ni], acc[mi][ni], 0, 0, 0);
        }
    }
#pragma unroll
    for (int mi = 0; mi < 4; mi++)
#pragma unroll
        for (int ni = 0; ni < 4; ni++) {
            int n = n0 + wn + ni * 16 + l15;
            float bv = bias[n];
#pragma unroll
            for (int r = 0; r < 4; r++) {
                int mg = m0 + wm + mi * 16 + quad * 4 + r;
                xout[mg * 1024 + n] = acc[mi][ni][r] + bv + resid[mg * 1024 + n];
            }
        }
}

// ---------------- flash attention: double-buffered DMA, 64-kv tiles --------
// grid 1024 blocks of 256 (4 waves).  Block = 64 q of one (b,h) x kv-half
// (2048, 32 tiles of 64).  Wave w: qsub = w&1 (32 q), kvsub = w>>1 (32 kv of
// each tile).  Loop: { barrier; stage(kt+1)->other buf; compute(kt) }.
// End: kvsub partials merged in-block through the (dead) staging LDS ->
// ONE partial per (bhalf) -> Osc[2][32][64][1024], Lsc[2][32][1024].
__global__ __launch_bounds__(256, 4) void attn_kernel(
    const unsigned short* __restrict__ Q,   // [B,NH,1024,64]
    const unsigned short* __restrict__ K,   // [B,NH,4096,64]  masked rows = 0
    const unsigned short* __restrict__ VT,  // [B,NH,64,4096]  masked cols = 0
    float* __restrict__ Osc,                // [2][32][64][1024] fp32 partial O^T
    float* __restrict__ Lsc)                // [2][32][1024] partial l
{
    __shared__ __align__(16) union {
        struct { unsigned short Kb[2][4096]; unsigned short Vb[2][4096]; } st;
        struct { float OL[2][2048]; float ls[64]; } mg;
    } sm;

    int tid  = threadIdx.x;
    int lane = tid & 63;
    int w    = tid >> 6;
    int wvu  = __builtin_amdgcn_readfirstlane(w);
    int l31  = lane & 31, hw = lane >> 5;
    int qsub = w & 1, kvsub = w >> 1;

    // XCD-grouped: 4 (b,h) per XCD; q-tiles and halves of one bh share L2
    int bid  = blockIdx.x;
    int xcd  = bid & 7, gidx = bid >> 3;
    int bh   = xcd * 4 + (gidx & 3);
    int rest = gidx >> 2;                    // 0..31
    int q0   = (rest & 15) * 64;
    int bhalf = rest >> 4;

    const unsigned short* Kb = K + ((long)bh * 4096 + bhalf * 2048) * HD;
    const unsigned short* Vb = VT + (long)bh * HD * 4096 + bhalf * 2048;
    const unsigned short* Qb = Q + ((long)bh * 1024 + q0) * HD;

    // Q fragments (B-operand): B[n=q=l31][k=hw*8+j], 4 k-chunks of 16
    bf16x8_t qfr[4];
#pragma unroll
    for (int ks = 0; ks < 4; ks++)
        qfr[ks] = ld16g(Qb + (qsub * 32 + l31) * HD + ks * 16 + hw * 8);

    f32x16_t oacc[2];
    oacc[0] = (f32x16_t)(0.f); oacc[1] = (f32x16_t)(0.f);
    float l_run = 0.f;

    auto stage = [&](int kt, int bufi) {
#pragma unroll
        for (int i = 0; i < 2; i++) {
            int s = (i * 4 + wvu) * 64 + lane;            // 0..511 slots of 16B
            int row = s >> 3, pc = ((s & 7) ^ (row & 7)) << 3;
            gld16(&Kb[(long)(kt * 64 + row) * HD + pc], &sm.st.Kb[bufi][(i * 4 + wvu) * 512]);
            gld16(&Vb[(long)row * 4096 + kt * 64 + pc], &sm.st.Vb[bufi][(i * 4 + wvu) * 512]);
        }
    };

    const char* Kc = (const char*)sm.st.Kb;
    const char* Vc = (const char*)sm.st.Vb;

    stage(0, 0);
#pragma unroll 2
    for (int kt = 0; kt < 32; kt++) {
        __syncthreads();                 // stage(kt) visible; compute(kt-1) done
        if (kt + 1 < 32) stage(kt + 1, (kt + 1) & 1);
        int bo = (kt & 1) * 8192;        // byte offset of current buffer

        // ---- S^T: C[kv32][q32], kv rows = kvsub*32 + l31 ----
        f32x16_t sa = (f32x16_t)(0.f);
        int krow = kvsub * 32 + l31;
#pragma unroll
        for (int ks = 0; ks < 4; ks++) {
            int phys = (ks * 2 + hw) ^ (krow & 7);
            bf16x8_t kf = *reinterpret_cast<const bf16x8_t*>(
                Kc + bo + krow * 128 + phys * 16);
            sa = __builtin_amdgcn_mfma_f32_32x32x16_bf16(kf, qfr[ks], sa, 0, 0, 0);
        }

        // ---- fixed-m softmax: p = 2^(s*c - 10) ----
        float pv[16];
        float rs = 0.f;
#pragma unroll
        for (int r = 0; r < 16; r++) {
            pv[r] = exp2f(fmaf(sa[r], SCALE_L2E, -FIXM));
            rs += pv[r];
        }
        l_run += rs;
        unsigned pku[8];
#pragma unroll
        for (int s4 = 0; s4 < 4; s4++) {
            pku[s4 * 2 + 0] = pack_bf16(pv[s4 * 4 + 0], pv[s4 * 4 + 1]);
            pku[s4 * 2 + 1] = pack_bf16(pv[s4 * 4 + 2], pv[s4 * 4 + 3]);
        }

        // ---- PV: O^T[d][q] += V^T · P over the wave's 32-kv strip ----
#pragma unroll
        for (int ks2 = 0; ks2 < 2; ks2++) {
            int s_lo = ks2 * 2, s_own = ks2 * 2 + hw;
            unsigned send0 = hw ? pku[s_lo * 2 + 0] : pku[(s_lo + 1) * 2 + 0];
            unsigned send1 = hw ? pku[s_lo * 2 + 1] : pku[(s_lo + 1) * 2 + 1];
            unsigned recv0 = __shfl_xor((int)send0, 32, 64);
            unsigned recv1 = __shfl_xor((int)send1, 32, 64);
            union { uint4 u; bf16x8_t f; } bw;
            bw.u.x = hw ? recv0 : pku[s_own * 2 + 0];
            bw.u.y = hw ? recv1 : pku[s_own * 2 + 1];
            bw.u.z = hw ? pku[s_own * 2 + 0] : recv0;
            bw.u.w = hw ? pku[s_own * 2 + 1] : recv1;
            int c = kvsub * 4 + ks2 * 2 + hw;            // kv 8-chunk index
#pragma unroll
            for (int ds = 0; ds < 2; ds++) {
                int vrow = ds * 32 + l31;
                int phys = c ^ (vrow & 7);
                bf16x8_t va = *reinterpret_cast<const bf16x8_t*>(
                    Vc + bo + vrow * 128 + phys * 16);
                oacc[ds] = __builtin_amdgcn_mfma_f32_32x32x16_bf16(
                    va, bw.f, oacc[ds], 0, 0, 0);
            }
        }
    }

    // ---- in-block kvsub merge through the (dead) staging LDS ----
    l_run += __shfl_xor(l_run, 32, 64);
    __syncthreads();                     // all staging reads done; LDS reusable
    if (kvsub == 1) {
        float* OL = sm.mg.OL[qsub];
#pragma unroll
        for (int ds = 0; ds < 2; ds++)
#pragma unroll
            for (int r = 0; r < 16; r++) {
                int d = ds * 32 + (r & 3) + 8 * (r >> 2) + 4 * hw;
                OL[d * 32 + l31] = oacc[ds][r];
            }
        if (hw == 0) sm.mg.ls[qsub * 32 + l31] = l_run;
    }
    __syncthreads();
    if (kvsub == 0) {
        const float* OL = sm.mg.OL[qsub];
        int q = q0 + qsub * 32 + l31;
        long obase = (((long)bhalf * 32 + bh) * 64) * 1024;
#pragma unroll
        for (int ds = 0; ds < 2; ds++)
#pragma unroll
            for (int r = 0; r < 16; r++) {
                int d = ds * 32 + (r & 3) + 8 * (r >> 2) + 4 * hw;
                Osc[obase + (long)d * 1024 + q] = oacc[ds][r] + OL[d * 32 + l31];
            }
        if (hw == 0)
            Lsc[((long)bhalf * 32 + bh) * 1024 + q] = l_run + sm.mg.ls[qsub * 32 + l31];
    }
}

// ---------------- merge 2 partials, normalize, transpose to AO -------------
__global__ __launch_bounds__(256) void attn_merge(
    const float* __restrict__ Osc, const float* __restrict__ Lsc,
    const float* __restrict__ Sub, unsigned short* __restrict__ AO)
{
    __shared__ unsigned short T[64 * 66];
    int t = threadIdx.x, w = t >> 6, lane = t & 63;
    int bh = blockIdx.y, b = bh >> 4, h = bh & 15;
    int q0 = blockIdx.x * 64;
    int q = q0 + lane;

    float ls = Lsc[(long)bh * 1024 + q]
             + Lsc[(long)(32 + bh) * 1024 + q] - Sub[b];
    float inv = __builtin_amdgcn_rcpf(ls);
    inv = inv * (2.f - ls * inv);            // NR refine

#pragma unroll
    for (int dd = 0; dd < 16; dd++) {
        int d = w * 16 + dd;
        long base = (long)bh * 64 * 1024 + (long)d * 1024 + q;
        float o = Osc[base] + Osc[base + 32l * 64 * 1024];
        T[lane * 66 + d] = f32_bf16(o * inv);
    }
    __syncthreads();
    int q2 = t >> 2, c16 = (t & 3) * 16;
    unsigned ov[8];
#pragma unroll
    for (int j = 0; j < 8; j++)
        ov[j] = *reinterpret_cast<const unsigned*>(&T[q2 * 66 + c16 + j * 2]);
    unsigned short* dst = &AO[((long)(b * 1024 + q0 + q2)) * E_DIM + h * HD + c16];
    reinterpret_cast<uint4*>(dst)[0] = make_uint4(ov[0], ov[1], ov[2], ov[3]);
    reinterpret_cast<uint4*>(dst)[1] = make_uint4(ov[4], ov[5], ov[6], ov[7]);
}

// ---------------- LayerNorm over E=1024 ------------------------------------
__global__ __launch_bounds__(256) void ln_kernel(
    const float* __restrict__ x, const float* __restrict__ g,
    const float* __restrict__ be, float* __restrict__ out)
{
    __shared__ float red[8];
    int row = blockIdx.x, tid = threadIdx.x;
    float4 v = reinterpret_cast<const float4*>(x)[row * 256 + tid];
    float s  = v.x + v.y + v.z + v.w;
    float sq = v.x * v.x + v.y * v.y + v.z * v.z + v.w * v.w;
#pragma unroll
    for (int off = 32; off >= 1; off >>= 1) {
        s  += __shfl_xor(s,  off, 64);
        sq += __shfl_xor(sq, off, 64);
    }
    if ((tid & 63) == 0) { red[tid >> 6] = s; red[4 + (tid >> 6)] = sq; }
    __syncthreads();
    s  = red[0] + red[1] + red[2] + red[3];
    sq = red[4] + red[5] + red[6] + red[7];
    float mu  = s * (1.f / 1024.f);
    float var = sq * (1.f / 1024.f) - mu * mu;
    float rs  = rsqrtf(var + 1e-5f);
    int c = tid * 4;
    float4 o;
    o.x = (v.x - mu) * rs * g[c]     + be[c];
    o.y = (v.y - mu) * rs * g[c + 1] + be[c + 1];
    o.z = (v.z - mu) * rs * g[c + 2] + be[c + 2];
    o.w = (v.w - mu) * rs * g[c + 3] + be[c + 3];
    reinterpret_cast<float4*>(out)[row * 256 + tid] = o;
}

// ---------------------------------------------------------------------------
extern "C" void kernel_launch(void* const* d_in, const int* in_sizes, int n_in,
                              void* d_out, int out_size, void* d_ws, size_t ws_size,
                              hipStream_t stream) {
    const float* query     = (const float*)d_in[0];
    const float* key_value = (const float*)d_in[1];
    const int*   kv_mask   = (const int*)d_in[2];
    const float* Wq = (const float*)d_in[3];
    const float* bq = (const float*)d_in[4];
    const float* Wk = (const float*)d_in[5];
    const float* bk = (const float*)d_in[6];
    const float* Wv = (const float*)d_in[7];
    const float* bv = (const float*)d_in[8];
    const float* Wo = (const float*)d_in[9];
    const float* bo = (const float*)d_in[10];
    const float* ln_g = (const float*)d_in[11];
    const float* ln_b = (const float*)d_in[12];
    float* out = (float*)d_out;

    // workspace layout (MiB). Osc (16 MB) overlays the cast buffers, which
    // are dead before attn_kernel runs (stream-ordered).
    char* ws = (char*)d_ws;
    unsigned short* Xq  = (unsigned short*)(ws);                     // 0-4
    unsigned short* Xkv = (unsigned short*)(ws + (4ll  << 20));      // 4-20
    unsigned short* Wqb = (unsigned short*)(ws + (20ll << 20));      // 20-22
    unsigned short* Wkb = (unsigned short*)(ws + (22ll << 20));      // 22-24
    unsigned short* Wvb = (unsigned short*)(ws + (24ll << 20));      // 24-26
    float*          Osc = (float*)(ws);                              // 0-16 (after gemms)
    unsigned short* Kh  = (unsigned short*)(ws + (32ll << 20));      // 32-48
    unsigned short* VTh = (unsigned short*)(ws + (48ll << 20));      // 48-64
    unsigned short* AO  = (unsigned short*)(ws + (64ll << 20));      // 64-68
    float*          Xr  = (float*)(ws + (68ll << 20));               // 68-76
    float*          Lsc = (float*)(ws + (76ll << 20));               // 76-76.25
    float*          Sub = (float*)(ws + (77ll << 20));               // tiny
    unsigned short* Qh  = (unsigned short*)(ws + (80ll << 20));      // 80-84
    unsigned short* Wob = (unsigned short*)(ws + (84ll << 20));      // 84-86

    cast_all<<<14338, 256, 0, stream>>>(query, key_value, Wq, Wk, Wv, Wo,
                                        Xq, Xkv, Wqb, Wkb, Wvb, Wob,
                                        kv_mask, Sub);

    gemm_kv<<<dim3(16, 64), 256, 0, stream>>>(Xkv, Wkb, Wvb, bk, bv, Kh, VTh, kv_mask);
    gemm_q<<<dim3(8, 16), 256, 0, stream>>>(Xq, Wqb, bq, Qh);

    attn_kernel<<<1024, 256, 0, stream>>>(Qh, Kh, VTh, Osc, Lsc);
    attn_merge<<<dim3(16, 32), 256, 0, stream>>>(Osc, Lsc, Sub, AO);

    gemm_oproj<<<dim3(8, 16), 256, 0, stream>>>(AO, Wob, bo, query, Xr);

    ln_kernel<<<2048, 256, 0, stream>>>(Xr, ln_g, ln_b, out);
}

// Round 10
// 276.637 us; speedup vs baseline: 1.3683x; 1.0139x over previous
//
#include <hip/hip_runtime.h>
#include <cstdint>

// ---------------------------------------------------------------------------
// CrossAttentionBlock: q/k/v proj (bf16 MFMA; K/V rows zeroed where masked;
// Q pre-scaled by log2(e)/8) -> flash attention (32x32 MFMA, exp2-only
// softmax, double-buffered DMA staging, wave specialization qsub x kvsub,
// in-block kvsub merge, pure-sum partials) -> merge(+transpose) -> o proj
// (+residual) -> LayerNorm.  B=2,SQ=1024,SKV=4096,E=1024,H=16,D=64.
// Softmax: p = 2^(s') with s' = K·(Q*log2(e)/8) bounded (|s'|<~10, no
// overflow, no max needed). Masked kv have K=V=0 => s'==0 => p=1 exactly;
// contributes 0 to O and n_masked*1.0 to l (subtracted at merge).
// R5: never cap launch_bounds below live set (spill).  R6: stage-then-barrier
// drains DMA.  R7: register-direct chains on L2 latency.  R8: {barrier;
// stage(kt+1); compute(kt)} hides DMA with one barrier/tile.
// R10: full-GPU grids for small GEMMs; mask loads hoisted; FIXM dropped.
// ---------------------------------------------------------------------------

typedef __bf16 bf16x8_t  __attribute__((ext_vector_type(8)));
typedef float  f32x4_t   __attribute__((ext_vector_type(4)));
typedef float  f32x16_t  __attribute__((ext_vector_type(16)));

#define E_DIM 1024
#define NH    16
#define HD    64
#define SCALE_L2E 0.1803368804f   // (1/8) * log2(e)

__device__ __forceinline__ unsigned short f32_bf16(float f) {
    union { float f; unsigned int u; } v; v.f = f;
    unsigned int u = v.u;
    unsigned int r = (u + 0x7fffu + ((u >> 16) & 1u)) >> 16;  // RNE
    return (unsigned short)r;
}

__device__ __forceinline__ unsigned pack_bf16(float a, float b) {
    __bf16 x = (__bf16)a, y = (__bf16)b;
    unsigned short ux = __builtin_bit_cast(unsigned short, x);
    unsigned short uy = __builtin_bit_cast(unsigned short, y);
    return (unsigned)ux | ((unsigned)uy << 16);
}

// async global->LDS, 16B per lane; lds base must be wave-uniform
__device__ __forceinline__ void gld16(const unsigned short* g, unsigned short* l) {
    __builtin_amdgcn_global_load_lds(
        (const __attribute__((address_space(1))) unsigned int*)g,
        (__attribute__((address_space(3))) unsigned int*)l, 16, 0, 0);
}

__device__ __forceinline__ bf16x8_t ld16g(const unsigned short* p) {
    union { uint4 u; bf16x8_t f; } v;
    v.u = *reinterpret_cast<const uint4*>(p);
    return v.f;
}

// ------- fused fp32 -> bf16 casts (all 6 tensors) + mask count -------------
__global__ void cast_all(const float* __restrict__ q, const float* __restrict__ kv,
                         const float* __restrict__ wq, const float* __restrict__ wk,
                         const float* __restrict__ wv, const float* __restrict__ wo,
                         unsigned short* __restrict__ Xq, unsigned short* __restrict__ Xkv,
                         unsigned short* __restrict__ Wqb, unsigned short* __restrict__ Wkb,
                         unsigned short* __restrict__ Wvb, unsigned short* __restrict__ Wob,
                         const int* __restrict__ msk, float* __restrict__ Sub) {
    __shared__ int red[4];
    if (blockIdx.x >= 14336) {           // mask-count blocks (b = 0,1)
        int b = blockIdx.x - 14336, t = threadIdx.x;
        int s = 0;
#pragma unroll
        for (int k = 0; k < 16; k++) s += (msk[b * 4096 + k * 256 + t] != 0);
#pragma unroll
        for (int off = 32; off >= 1; off >>= 1) s += __shfl_xor(s, off, 64);
        if ((t & 63) == 0) red[t >> 6] = s;
        __syncthreads();
        if (t == 0)
            Sub[b] = (float)(4096 - (red[0] + red[1] + red[2] + red[3]));
        return;
    }
    long i = (long)blockIdx.x * 256 + threadIdx.x;   // float4 index
    const float* src; unsigned short* dst; long off;
    if (i < 2621440) {
        if (i < 524288) { src = q;  dst = Xq;  off = i; }
        else            { src = kv; dst = Xkv; off = i - 524288; }
    } else {
        long j = i - 2621440;
        int w = (int)(j >> 18); off = j & 262143;
        src = (w == 0) ? wq : (w == 1) ? wk : (w == 2) ? wv : wo;
        dst = (w == 0) ? Wqb : (w == 1) ? Wkb : (w == 2) ? Wvb : Wob;
    }
    float4 v = reinterpret_cast<const float4*>(src)[off];
    ushort4 o;
    o.x = f32_bf16(v.x); o.y = f32_bf16(v.y);
    o.z = f32_bf16(v.z); o.w = f32_bf16(v.w);
    reinterpret_cast<ushort4*>(dst)[off] = o;
}

// ---------------- GEMM bodies (m97-style staging) --------------------------
#define BK 64

// Q projection, BM=64 x BN=128 (grid (8,32) = 256 blocks, full GPU).
// out [B,H,S,D] bf16, PRE-SCALED by SCALE_L2E for the attention softmax.
__global__ __launch_bounds__(256) void gemm_q(
    const unsigned short* __restrict__ A,
    const unsigned short* __restrict__ W,
    const float* __restrict__ bias,
    unsigned short* __restrict__ out)
{
    __shared__ __align__(16) unsigned short As[64 * BK];
    __shared__ __align__(16) unsigned short Bs[128 * BK];
    int tid  = threadIdx.x;
    int m0   = blockIdx.y * 64;
    int n0   = blockIdx.x * 128;
    int lane = tid & 63;
    int wvu  = __builtin_amdgcn_readfirstlane(tid >> 6);
    int l15  = lane & 15, quad = lane >> 4, x7 = l15 & 7;
    int wm   = ((tid >> 6) >> 1) * 32, wn = ((tid >> 6) & 1) * 64;

    f32x4_t acc[2][4];
#pragma unroll
    for (int i = 0; i < 2; i++)
#pragma unroll
        for (int j = 0; j < 4; j++) acc[i][j] = (f32x4_t)(0.f);

    for (int k0 = 0; k0 < 1024; k0 += BK) {
        __syncthreads();
#pragma unroll
        for (int i = 0; i < 2; i++) {       // A: 512 slots
            int s = (i * 4 + wvu) * 64 + lane;
            int row = s >> 3, pcol = ((s & 7) ^ (row & 7)) << 3;
            gld16(&A[(long)(m0 + row) * 1024 + k0 + pcol], &As[(i * 4 + wvu) * 512]);
        }
#pragma unroll
        for (int i = 0; i < 4; i++) {       // B: 1024 slots
            int s = (i * 4 + wvu) * 64 + lane;
            int row = s >> 3, pcol = ((s & 7) ^ (row & 7)) << 3;
            gld16(&W[(long)(n0 + row) * 1024 + k0 + pcol], &Bs[(i * 4 + wvu) * 512]);
        }
        __syncthreads();
        const char* Ab = (const char*)As;
        const char* Bb = (const char*)Bs;
#pragma unroll
        for (int ks = 0; ks < 2; ks++) {
            int pos = (((ks << 2) + quad) ^ x7) << 4;
            bf16x8_t af[2], bf[4];
#pragma unroll
            for (int mi = 0; mi < 2; mi++)
                af[mi] = *reinterpret_cast<const bf16x8_t*>(
                    Ab + (wm + mi * 16 + l15) * 128 + pos);
#pragma unroll
            for (int ni = 0; ni < 4; ni++)
                bf[ni] = *reinterpret_cast<const bf16x8_t*>(
                    Bb + (wn + ni * 16 + l15) * 128 + pos);
#pragma unroll
            for (int mi = 0; mi < 2; mi++)
#pragma unroll
                for (int ni = 0; ni < 4; ni++)
                    acc[mi][ni] = __builtin_amdgcn_mfma_f32_16x16x32_bf16(
                        af[mi], bf[ni], acc[mi][ni], 0, 0, 0);
        }
    }
#pragma unroll
    for (int mi = 0; mi < 2; mi++)
#pragma unroll
        for (int ni = 0; ni < 4; ni++) {
            int n = n0 + wn + ni * 16 + l15;
            float bv = bias[n];
            int h = n >> 6, d = n & 63;
#pragma unroll
            for (int r = 0; r < 4; r++) {
                int mg = m0 + wm + mi * 16 + quad * 4 + r;
                int b = mg >> 10, s = mg & 1023;
                out[(((b * NH + h) << 10) + s) * HD + d] =
                    f32_bf16((acc[mi][ni][r] + bv) * SCALE_L2E);
            }
        }
}

// K + V^T projections fused: grid (16,64); bx<8 -> K [B,H,S,D] masked-row-0,
// bx>=8 -> V^T [B,H,D,S] masked-col-0.  BM=BN=128.
__global__ __launch_bounds__(256) void gemm_kv(
    const unsigned short* __restrict__ A,
    const unsigned short* __restrict__ Wk,
    const unsigned short* __restrict__ Wv,
    const float* __restrict__ bk,
    const float* __restrict__ bv,
    unsigned short* __restrict__ Kout,
    unsigned short* __restrict__ Vout,
    const int* __restrict__ kvm)
{
    __shared__ __align__(16) unsigned short As[128 * BK];
    __shared__ __align__(16) unsigned short Bs[128 * BK];
    int tid  = threadIdx.x;
    int bx   = blockIdx.x;
    int isV  = bx >= 8;
    int m0   = blockIdx.y * 128;
    int n0   = (bx & 7) * 128;
    const unsigned short* W = isV ? Wv : Wk;
    const float* bias = isV ? bv : bk;
    int lane = tid & 63;
    int wvu  = __builtin_amdgcn_readfirstlane(tid >> 6);
    int l15  = lane & 15, quad = lane >> 4, x7 = l15 & 7;
    int wm   = ((tid >> 6) >> 1) * 64, wn = ((tid >> 6) & 1) * 64;

    f32x4_t acc[4][4];
#pragma unroll
    for (int i = 0; i < 4; i++)
#pragma unroll
        for (int j = 0; j < 4; j++) acc[i][j] = (f32x4_t)(0.f);

    for (int k0 = 0; k0 < 1024; k0 += BK) {
        __syncthreads();
#pragma unroll
        for (int i = 0; i < 4; i++) {
            int s = (i * 4 + wvu) * 64 + lane;
            int row = s >> 3, pcol = ((s & 7) ^ (row & 7)) << 3;
            gld16(&A[(long)(m0 + row) * 1024 + k0 + pcol], &As[(i * 4 + wvu) * 512]);
            gld16(&W[(long)(n0 + row) * 1024 + k0 + pcol], &Bs[(i * 4 + wvu) * 512]);
        }
        __syncthreads();
        const char* Ab = (const char*)As;
        const char* Bb = (const char*)Bs;
#pragma unroll
        for (int ks = 0; ks < 2; ks++) {
            int pos = (((ks << 2) + quad) ^ x7) << 4;
            bf16x8_t af[4], bf[4];
#pragma unroll
            for (int mi = 0; mi < 4; mi++)
                af[mi] = *reinterpret_cast<const bf16x8_t*>(
                    Ab + (wm + mi * 16 + l15) * 128 + pos);
#pragma unroll
            for (int ni = 0; ni < 4; ni++)
                bf[ni] = *reinterpret_cast<const bf16x8_t*>(
                    Bb + (wn + ni * 16 + l15) * 128 + pos);
#pragma unroll
            for (int mi = 0; mi < 4; mi++)
#pragma unroll
                for (int ni = 0; ni < 4; ni++)
                    acc[mi][ni] = __builtin_amdgcn_mfma_f32_16x16x32_bf16(
                        af[mi], bf[ni], acc[mi][ni], 0, 0, 0);
        }
    }
    // hoisted mask: mg = b*4096+s indexes kvm flat; int4 per mi
    int4 mk[4];
#pragma unroll
    for (int mi = 0; mi < 4; mi++) {
        int mg0 = m0 + wm + mi * 16 + quad * 4;
        mk[mi] = *reinterpret_cast<const int4*>(&kvm[mg0]);
    }
    if (!isV) {
#pragma unroll
        for (int mi = 0; mi < 4; mi++)
#pragma unroll
            for (int ni = 0; ni < 4; ni++) {
                int n = n0 + wn + ni * 16 + l15;
                float bvv = bias[n];
                int h = n >> 6, d = n & 63;
#pragma unroll
                for (int r = 0; r < 4; r++) {
                    int mg = m0 + wm + mi * 16 + quad * 4 + r;
                    int b = mg >> 12, s = mg & 4095;
                    unsigned short val = (&mk[mi].x)[r]
                        ? f32_bf16(acc[mi][ni][r] + bvv) : (unsigned short)0;
                    Kout[(((b * NH + h) << 12) + s) * HD + d] = val;
                }
            }
    } else {
#pragma unroll
        for (int mi = 0; mi < 4; mi++)
#pragma unroll
            for (int ni = 0; ni < 4; ni++) {
                int n = n0 + wn + ni * 16 + l15;
                float bvv = bias[n];
                int h = n >> 6, d = n & 63;
                int mg0 = m0 + wm + mi * 16 + quad * 4;
                int b = mg0 >> 12, s = mg0 & 4095;
                ushort4 w;
                w.x = mk[mi].x ? f32_bf16(acc[mi][ni][0] + bvv) : (unsigned short)0;
                w.y = mk[mi].y ? f32_bf16(acc[mi][ni][1] + bvv) : (unsigned short)0;
                w.z = mk[mi].z ? f32_bf16(acc[mi][ni][2] + bvv) : (unsigned short)0;
                w.w = mk[mi].w ? f32_bf16(acc[mi][ni][3] + bvv) : (unsigned short)0;
                *reinterpret_cast<ushort4*>(
                    &Vout[(((b * NH + h) * HD + d) << 12) + s]) = w;
            }
    }
}

// -------- O-proj GEMM + bias + residual -> fp32, BM=64 (256 blocks) --------
__global__ __launch_bounds__(256) void gemm_oproj(
    const unsigned short* __restrict__ A,
    const unsigned short* __restrict__ W,
    const float* __restrict__ bias,
    const float* __restrict__ resid,
    float* __restrict__ xout)
{
    __shared__ __align__(16) unsigned short As[64 * BK];
    __shared__ __align__(16) unsigned short Bs[128 * BK];
    int tid  = threadIdx.x;
    int m0   = blockIdx.y * 64;
    int n0   = blockIdx.x * 128;
    int lane = tid & 63;
    int wvu  = __builtin_amdgcn_readfirstlane(tid >> 6);
    int l15  = lane & 15, quad = lane >> 4, x7 = l15 & 7;
    int wm   = ((tid >> 6) >> 1) * 32, wn = ((tid >> 6) & 1) * 64;

    f32x4_t acc[2][4];
#pragma unroll
    for (int i = 0; i < 2; i++)
#pragma unroll
        for (int j = 0; j < 4; j++) acc[i][j] = (f32x4_t)(0.f);

    for (int k0 = 0; k0 < 1024; k0 += BK) {
        __syncthreads();
#pragma unroll
        for (int i = 0; i < 2; i++) {
            int s = (i * 4 + wvu) * 64 + lane;
            int row = s >> 3, pcol = ((s & 7) ^ (row & 7)) << 3;
            gld16(&A[(long)(m0 + row) * 1024 + k0 + pcol], &As[(i * 4 + wvu) * 512]);
        }
#pragma unroll
        for (int i = 0; i < 4; i++) {
            int s = (i * 4 + wvu) * 64 + lane;
            int row = s >> 3, pcol = ((s & 7) ^ (row & 7)) << 3;
            gld16(&W[(long)(n0 + row) * 1024 + k0 + pcol], &Bs[(i * 4 + wvu) * 512]);
        }
        __syncthreads();
        const char* Ab = (const char*)As;
        const char* Bb = (const char*)Bs;
#pragma unroll
        for (int ks = 0; ks < 2; ks++) {
            int pos = (((ks << 2) + quad) ^ x7) << 4;
            bf16x8_t af[2], bf[4];
#pragma unroll
            for (int mi = 0; mi < 2; mi++)
                af[mi] = *reinterpret_cast<const bf16x8_t*>(
                    Ab + (wm + mi * 16 + l15) * 128 + pos);
#pragma unroll
            for (int ni = 0; ni < 4; ni++)
                bf[ni] = *reinterpret_cast<const bf16x8_t*>(
                    Bb + (wn + ni * 16 + l15) * 128 + pos);
#pragma unroll
            for (int mi = 0; mi < 2; mi++)
#pragma unroll
                for (int ni = 0; ni < 4; ni++)
                    acc[mi][ni] = __builtin_amdgcn_mfma_f32_16x16x32_bf16(
                        af[mi], bf[ni], acc[mi][ni], 0, 0, 0);
        }
    }
#pragma unroll
    for (int mi = 0; mi < 2; mi++)
#pragma unroll
        for (int ni = 0; ni < 4; ni++) {
            int n = n0 + wn + ni * 16 + l15;
            float bv = bias[n];
#pragma unroll
            for (int r = 0; r < 4; r++) {
                int mg = m0 + wm + mi * 16 + quad * 4 + r;
                xout[mg * 1024 + n] = acc[mi][ni][r] + bv + resid[mg * 1024 + n];
            }
        }
}

// ---------------- flash attention: double-buffered DMA, 64-kv tiles --------
// grid 1024 blocks of 256 (4 waves).  Block = 64 q of one (b,h) x kv-half
// (2048, 32 tiles of 64).  Wave w: qsub = w&1 (32 q), kvsub = w>>1 (32 kv of
// each tile).  Loop: { barrier; stage(kt+1)->other buf; compute(kt) }.
// Softmax: p = exp2(s') directly (Q pre-scaled; no FIXM, no max).
// End: kvsub partials merged in-block through the (dead) staging LDS.
__global__ __launch_bounds__(256, 4) void attn_kernel(
    const unsigned short* __restrict__ Q,   // [B,NH,1024,64] pre-scaled
    const unsigned short* __restrict__ K,   // [B,NH,4096,64]  masked rows = 0
    const unsigned short* __restrict__ VT,  // [B,NH,64,4096]  masked cols = 0
    float* __restrict__ Osc,                // [2][32][64][1024] fp32 partial O^T
    float* __restrict__ Lsc)                // [2][32][1024] partial l
{
    __shared__ __align__(16) union {
        struct { unsigned short Kb[2][4096]; unsigned short Vb[2][4096]; } st;
        struct { float OL[2][2048]; float ls[64]; } mg;
    } sm;

    int tid  = threadIdx.x;
    int lane = tid & 63;
    int w    = tid >> 6;
    int wvu  = __builtin_amdgcn_readfirstlane(w);
    int l31  = lane & 31, hw = lane >> 5;
    int qsub = w & 1, kvsub = w >> 1;

    // XCD-grouped: 4 (b,h) per XCD; q-tiles and halves of one bh share L2
    int bid  = blockIdx.x;
    int xcd  = bid & 7, gidx = bid >> 3;
    int bh   = xcd * 4 + (gidx & 3);
    int rest = gidx >> 2;                    // 0..31
    int q0   = (rest & 15) * 64;
    int bhalf = rest >> 4;

    const unsigned short* Kb = K + ((long)bh * 4096 + bhalf * 2048) * HD;
    const unsigned short* Vb = VT + (long)bh * HD * 4096 + bhalf * 2048;
    const unsigned short* Qb = Q + ((long)bh * 1024 + q0) * HD;

    // Q fragments (B-operand): B[n=q=l31][k=hw*8+j], 4 k-chunks of 16
    bf16x8_t qfr[4];
#pragma unroll
    for (int ks = 0; ks < 4; ks++)
        qfr[ks] = ld16g(Qb + (qsub * 32 + l31) * HD + ks * 16 + hw * 8);

    f32x16_t oacc[2];
    oacc[0] = (f32x16_t)(0.f); oacc[1] = (f32x16_t)(0.f);
    float l_run = 0.f;

    auto stage = [&](int kt, int bufi) {
#pragma unroll
        for (int i = 0; i < 2; i++) {
            int s = (i * 4 + wvu) * 64 + lane;            // 0..511 slots of 16B
            int row = s >> 3, pc = ((s & 7) ^ (row & 7)) << 3;
            gld16(&Kb[(long)(kt * 64 + row) * HD + pc], &sm.st.Kb[bufi][(i * 4 + wvu) * 512]);
            gld16(&Vb[(long)row * 4096 + kt * 64 + pc], &sm.st.Vb[bufi][(i * 4 + wvu) * 512]);
        }
    };

    const char* Kc = (const char*)sm.st.Kb;
    const char* Vc = (const char*)sm.st.Vb;

    stage(0, 0);
#pragma unroll 2
    for (int kt = 0; kt < 32; kt++) {
        __syncthreads();                 // stage(kt) visible; compute(kt-1) done
        if (kt + 1 < 32) stage(kt + 1, (kt + 1) & 1);
        int bo = (kt & 1) * 8192;        // byte offset of current buffer

        // ---- S^T: C[kv32][q32], kv rows = kvsub*32 + l31 ----
        f32x16_t sa = (f32x16_t)(0.f);
        int krow = kvsub * 32 + l31;
#pragma unroll
        for (int ks = 0; ks < 4; ks++) {
            int phys = (ks * 2 + hw) ^ (krow & 7);
            bf16x8_t kf = *reinterpret_cast<const bf16x8_t*>(
                Kc + bo + krow * 128 + phys * 16);
            sa = __builtin_amdgcn_mfma_f32_32x32x16_bf16(kf, qfr[ks], sa, 0, 0, 0);
        }

        // ---- softmax: p = 2^s' (Q pre-scaled; masked => s'=0 => p=1) ----
        float pv[16];
        float rs = 0.f;
#pragma unroll
        for (int r = 0; r < 16; r++) {
            pv[r] = exp2f(sa[r]);
            rs += pv[r];
        }
        l_run += rs;
        unsigned pku[8];
#pragma unroll
        for (int s4 = 0; s4 < 4; s4++) {
            pku[s4 * 2 + 0] = pack_bf16(pv[s4 * 4 + 0], pv[s4 * 4 + 1]);
            pku[s4 * 2 + 1] = pack_bf16(pv[s4 * 4 + 2], pv[s4 * 4 + 3]);
        }

        // ---- PV: O^T[d][q] += V^T · P over the wave's 32-kv strip ----
#pragma unroll
        for (int ks2 = 0; ks2 < 2; ks2++) {
            int s_lo = ks2 * 2, s_own = ks2 * 2 + hw;
            unsigned send0 = hw ? pku[s_lo * 2 + 0] : pku[(s_lo + 1) * 2 + 0];
            unsigned send1 = hw ? pku[s_lo * 2 + 1] : pku[(s_lo + 1) * 2 + 1];
            unsigned recv0 = __shfl_xor((int)send0, 32, 64);
            unsigned recv1 = __shfl_xor((int)send1, 32, 64);
            union { uint4 u; bf16x8_t f; } bw;
            bw.u.x = hw ? recv0 : pku[s_own * 2 + 0];
            bw.u.y = hw ? recv1 : pku[s_own * 2 + 1];
            bw.u.z = hw ? pku[s_own * 2 + 0] : recv0;
            bw.u.w = hw ? pku[s_own * 2 + 1] : recv1;
            int c = kvsub * 4 + ks2 * 2 + hw;            // kv 8-chunk index
#pragma unroll
            for (int ds = 0; ds < 2; ds++) {
                int vrow = ds * 32 + l31;
                int phys = c ^ (vrow & 7);
                bf16x8_t va = *reinterpret_cast<const bf16x8_t*>(
                    Vc + bo + vrow * 128 + phys * 16);
                oacc[ds] = __builtin_amdgcn_mfma_f32_32x32x16_bf16(
                    va, bw.f, oacc[ds], 0, 0, 0);
            }
        }
    }

    // ---- in-block kvsub merge through the (dead) staging LDS ----
    l_run += __shfl_xor(l_run, 32, 64);
    __syncthreads();                     // all staging reads done; LDS reusable
    if (kvsub == 1) {
        float* OL = sm.mg.OL[qsub];
#pragma unroll
        for (int ds = 0; ds < 2; ds++)
#pragma unroll
            for (int r = 0; r < 16; r++) {
                int d = ds * 32 + (r & 3) + 8 * (r >> 2) + 4 * hw;
                OL[d * 32 + l31] = oacc[ds][r];
            }
        if (hw == 0) sm.mg.ls[qsub * 32 + l31] = l_run;
    }
    __syncthreads();
    if (kvsub == 0) {
        const float* OL = sm.mg.OL[qsub];
        int q = q0 + qsub * 32 + l31;
        long obase = (((long)bhalf * 32 + bh) * 64) * 1024;
#pragma unroll
        for (int ds = 0; ds < 2; ds++)
#pragma unroll
            for (int r = 0; r < 16; r++) {
                int d = ds * 32 + (r & 3) + 8 * (r >> 2) + 4 * hw;
                Osc[obase + (long)d * 1024 + q] = oacc[ds][r] + OL[d * 32 + l31];
            }
        if (hw == 0)
            Lsc[((long)bhalf * 32 + bh) * 1024 + q] = l_run + sm.mg.ls[qsub * 32 + l31];
    }
}

// ---------------- merge 2 partials, normalize, transpose to AO -------------
__global__ __launch_bounds__(256) void attn_merge(
    const float* __restrict__ Osc, const float* __restrict__ Lsc,
    const float* __restrict__ Sub, unsigned short* __restrict__ AO)
{
    __shared__ unsigned short T[64 * 66];
    int t = threadIdx.x, w = t >> 6, lane = t & 63;
    int bh = blockIdx.y, b = bh >> 4, h = bh & 15;
    int q0 = blockIdx.x * 64;
    int q = q0 + lane;

    float ls = Lsc[(long)bh * 1024 + q]
             + Lsc[(long)(32 + bh) * 1024 + q] - Sub[b];
    float inv = __builtin_amdgcn_rcpf(ls);
    inv = inv * (2.f - ls * inv);            // NR refine

#pragma unroll
    for (int dd = 0; dd < 16; dd++) {
        int d = w * 16 + dd;
        long base = (long)bh * 64 * 1024 + (long)d * 1024 + q;
        float o = Osc[base] + Osc[base + 32l * 64 * 1024];
        T[lane * 66 + d] = f32_bf16(o * inv);
    }
    __syncthreads();
    int q2 = t >> 2, c16 = (t & 3) * 16;
    unsigned ov[8];
#pragma unroll
    for (int j = 0; j < 8; j++)
        ov[j] = *reinterpret_cast<const unsigned*>(&T[q2 * 66 + c16 + j * 2]);
    unsigned short* dst = &AO[((long)(b * 1024 + q0 + q2)) * E_DIM + h * HD + c16];
    reinterpret_cast<uint4*>(dst)[0] = make_uint4(ov[0], ov[1], ov[2], ov[3]);
    reinterpret_cast<uint4*>(dst)[1] = make_uint4(ov[4], ov[5], ov[6], ov[7]);
}

// ---------------- LayerNorm over E=1024 ------------------------------------
__global__ __launch_bounds__(256) void ln_kernel(
    const float* __restrict__ x, const float* __restrict__ g,
    const float* __restrict__ be, float* __restrict__ out)
{
    __shared__ float red[8];
    int row = blockIdx.x, tid = threadIdx.x;
    float4 v = reinterpret_cast<const float4*>(x)[row * 256 + tid];
    float s  = v.x + v.y + v.z + v.w;
    float sq = v.x * v.x + v.y * v.y + v.z * v.z + v.w * v.w;
#pragma unroll
    for (int off = 32; off >= 1; off >>= 1) {
        s  += __shfl_xor(s,  off, 64);
        sq += __shfl_xor(sq, off, 64);
    }
    if ((tid & 63) == 0) { red[tid >> 6] = s; red[4 + (tid >> 6)] = sq; }
    __syncthreads();
    s  = red[0] + red[1] + red[2] + red[3];
    sq = red[4] + red[5] + red[6] + red[7];
    float mu  = s * (1.f / 1024.f);
    float var = sq * (1.f / 1024.f) - mu * mu;
    float rs  = rsqrtf(var + 1e-5f);
    int c = tid * 4;
    float4 o;
    o.x = (v.x - mu) * rs * g[c]     + be[c];
    o.y = (v.y - mu) * rs * g[c + 1] + be[c + 1];
    o.z = (v.z - mu) * rs * g[c + 2] + be[c + 2];
    o.w = (v.w - mu) * rs * g[c + 3] + be[c + 3];
    reinterpret_cast<float4*>(out)[row * 256 + tid] = o;
}

// ---------------------------------------------------------------------------
extern "C" void kernel_launch(void* const* d_in, const int* in_sizes, int n_in,
                              void* d_out, int out_size, void* d_ws, size_t ws_size,
                              hipStream_t stream) {
    const float* query     = (const float*)d_in[0];
    const float* key_value = (const float*)d_in[1];
    const int*   kv_mask   = (const int*)d_in[2];
    const float* Wq = (const float*)d_in[3];
    const float* bq = (const float*)d_in[4];
    const float* Wk = (const float*)d_in[5];
    const float* bk = (const float*)d_in[6];
    const float* Wv = (const float*)d_in[7];
    const float* bv = (const float*)d_in[8];
    const float* Wo = (const float*)d_in[9];
    const float* bo = (const float*)d_in[10];
    const float* ln_g = (const float*)d_in[11];
    const float* ln_b = (const float*)d_in[12];
    float* out = (float*)d_out;

    // workspace layout (MiB). Osc (16 MB) overlays the cast buffers, which
    // are dead before attn_kernel runs (stream-ordered).
    char* ws = (char*)d_ws;
    unsigned short* Xq  = (unsigned short*)(ws);                     // 0-4
    unsigned short* Xkv = (unsigned short*)(ws + (4ll  << 20));      // 4-20
    unsigned short* Wqb = (unsigned short*)(ws + (20ll << 20));      // 20-22
    unsigned short* Wkb = (unsigned short*)(ws + (22ll << 20));      // 22-24
    unsigned short* Wvb = (unsigned short*)(ws + (24ll << 20));      // 24-26
    float*          Osc = (float*)(ws);                              // 0-16 (after gemms)
    unsigned short* Kh  = (unsigned short*)(ws + (32ll << 20));      // 32-48
    unsigned short* VTh = (unsigned short*)(ws + (48ll << 20));      // 48-64
    unsigned short* AO  = (unsigned short*)(ws + (64ll << 20));      // 64-68
    float*          Xr  = (float*)(ws + (68ll << 20));               // 68-76
    float*          Lsc = (float*)(ws + (76ll << 20));               // 76-76.25
    float*          Sub = (float*)(ws + (77ll << 20));               // tiny
    unsigned short* Qh  = (unsigned short*)(ws + (80ll << 20));      // 80-84
    unsigned short* Wob = (unsigned short*)(ws + (84ll << 20));      // 84-86

    cast_all<<<14338, 256, 0, stream>>>(query, key_value, Wq, Wk, Wv, Wo,
                                        Xq, Xkv, Wqb, Wkb, Wvb, Wob,
                                        kv_mask, Sub);

    gemm_kv<<<dim3(16, 64), 256, 0, stream>>>(Xkv, Wkb, Wvb, bk, bv, Kh, VTh, kv_mask);
    gemm_q<<<dim3(8, 32), 256, 0, stream>>>(Xq, Wqb, bq, Qh);

    attn_kernel<<<1024, 256, 0, stream>>>(Qh, Kh, VTh, Osc, Lsc);
    attn_merge<<<dim3(16, 32), 256, 0, stream>>>(Osc, Lsc, Sub, AO);

    gemm_oproj<<<dim3(8, 32), 256, 0, stream>>>(AO, Wob, bo, query, Xr);

    ln_kernel<<<2048, 256, 0, stream>>>(Xr, ln_g, ln_b, out);
}